// Round 1
// baseline (2602.982 us; speedup 1.0000x reference)
//
#include <hip/hip_runtime.h>

#define Nn 50000
#define Ee 800000
#define FIN 32
#define Hh 96
#define EDIM 16
#define Bb 50

__device__ __forceinline__ float silu_f(float x) {
    return x / (1.0f + __expf(-x));
}

__device__ __forceinline__ int lower_bound_i(const int* a, int n, int v) {
    int lo = 0, hi = n;
    while (lo < hi) { int m = (lo + hi) >> 1; if (a[m] < v) lo = m + 1; else hi = m; }
    return lo;
}

// ---------------- encoder: h = x @ We + be ----------------
__global__ void k_encoder(const float* __restrict__ x, const float* __restrict__ We,
                          const float* __restrict__ be, float* __restrict__ h) {
    __shared__ float xs[16][FIN];
    __shared__ float Ws[FIN][Hh];
    int t = threadIdx.x;
    int n0 = blockIdx.x * 16;
    for (int i = t; i < FIN * Hh; i += 256) Ws[i / Hh][i % Hh] = We[i];
    for (int i = t; i < 16 * FIN; i += 256) {
        int n = n0 + i / FIN;
        xs[i / FIN][i % FIN] = (n < Nn) ? x[n * FIN + (i % FIN)] : 0.f;
    }
    __syncthreads();
    for (int idx = t; idx < 16 * Hh; idx += 256) {
        int nl = idx / Hh, j = idx % Hh;
        int n = n0 + nl;
        if (n >= Nn) continue;
        float acc = be[j];
        #pragma unroll
        for (int k = 0; k < FIN; k++) acc += xs[nl][k] * Ws[k][j];
        h[n * Hh + j] = acc;
    }
}

// ---------------- edge prep: d2 + dst histogram ----------------
__global__ void k_prep(const int* __restrict__ ei, const float* __restrict__ pos,
                       float* __restrict__ d2, int* __restrict__ counts) {
    int e = blockIdx.x * 256 + threadIdx.x;
    if (e >= Ee) return;
    int s = ei[e], d = ei[Ee + e];
    float dx = pos[s * 3 + 0] - pos[d * 3 + 0];
    float dy = pos[s * 3 + 1] - pos[d * 3 + 1];
    float dz = pos[s * 3 + 2] - pos[d * 3 + 2];
    d2[e] = dx * dx + dy * dy + dz * dz;
    atomicAdd(&counts[d], 1);
}

// ---------------- two-level exclusive scan -> rowstart ----------------
__global__ void k_scanA(const int* __restrict__ counts, int* __restrict__ rowstart,
                        int* __restrict__ bsums) {
    __shared__ int s[256];
    int b = blockIdx.x, t = threadIdx.x, i = b * 256 + t;
    int v = (i < Nn) ? counts[i] : 0;
    s[t] = v;
    __syncthreads();
    for (int off = 1; off < 256; off <<= 1) {
        int add = (t >= off) ? s[t - off] : 0;
        __syncthreads();
        s[t] += add;
        __syncthreads();
    }
    if (i < Nn) rowstart[i + 1] = s[t];
    if (t == 255) bsums[b] = s[255];
}

__global__ void k_scanB(int* __restrict__ bsums, int nb) {
    __shared__ int s[256];
    int t = threadIdx.x;
    int v = (t < nb) ? bsums[t] : 0;
    s[t] = v;
    __syncthreads();
    for (int off = 1; off < 256; off <<= 1) {
        int add = (t >= off) ? s[t - off] : 0;
        __syncthreads();
        s[t] += add;
        __syncthreads();
    }
    if (t < nb) bsums[t] = s[t] - v;  // exclusive block offsets
}

__global__ void k_scanC(int* __restrict__ rowstart, const int* __restrict__ bsums) {
    int b = blockIdx.x, t = threadIdx.x, i = b * 256 + t;
    if (i < Nn) rowstart[i + 1] += bsums[b];
    if (i == 0 && b == 0) rowstart[0] = 0;
}

// ---------------- CSR fill: perm = edges sorted by dst ----------------
__global__ void k_fill(const int* __restrict__ ei, const int* __restrict__ rowstart,
                       int* __restrict__ cur, int* __restrict__ perm) {
    int e = blockIdx.x * 256 + threadIdx.x;
    if (e >= Ee) return;
    int d = ei[Ee + e];
    int slot = rowstart[d] + atomicAdd(&cur[d], 1);
    perm[slot] = e;
}

// ---------------- per-layer: A = h@W1a, B = h@W1b, zero agg ----------------
__global__ __launch_bounds__(256, 2)
void k_AB(const float* __restrict__ h, const float* __restrict__ eW1l,
          float* __restrict__ A, float* __restrict__ Bm, float* __restrict__ agg) {
    __shared__ float hs[64][100];
    __shared__ float Ws[96][96];
    int t = threadIdx.x;
    int n0 = blockIdx.x * 64;
    for (int i = t; i < 64 * 96; i += 256) {
        int nl = i / 96, c = i % 96;
        int n = n0 + nl;
        float v = (n < Nn) ? h[n * 96 + c] : 0.f;
        hs[nl][c] = v;
        if (n < Nn) agg[n * 96 + c] = 0.f;
    }
    for (int i = t; i < 96 * 96; i += 256) Ws[i / 96][i % 96] = eW1l[i];
    __syncthreads();
    int tj = t >> 4, te = t & 15, j0 = tj * 6;
    // ---- phase A (rows 0..95 of eW1) ----
    {
        float acc[4][6];
        #pragma unroll
        for (int i = 0; i < 4; i++)
            #pragma unroll
            for (int c = 0; c < 6; c++) acc[i][c] = 0.f;
        #pragma unroll 4
        for (int k = 0; k < 96; k++) {
            float wv[6];
            #pragma unroll
            for (int c = 0; c < 6; c++) wv[c] = Ws[k][j0 + c];
            #pragma unroll
            for (int i = 0; i < 4; i++) {
                float hv = hs[te + 16 * i][k];
                #pragma unroll
                for (int c = 0; c < 6; c++) acc[i][c] += hv * wv[c];
            }
        }
        #pragma unroll
        for (int i = 0; i < 4; i++) {
            int n = n0 + te + 16 * i;
            if (n < Nn)
                #pragma unroll
                for (int c = 0; c < 6; c++) A[n * 96 + j0 + c] = acc[i][c];
        }
    }
    __syncthreads();
    for (int i = t; i < 96 * 96; i += 256) Ws[i / 96][i % 96] = eW1l[96 * 96 + i];
    __syncthreads();
    // ---- phase B (rows 96..191 of eW1) ----
    {
        float acc[4][6];
        #pragma unroll
        for (int i = 0; i < 4; i++)
            #pragma unroll
            for (int c = 0; c < 6; c++) acc[i][c] = 0.f;
        #pragma unroll 4
        for (int k = 0; k < 96; k++) {
            float wv[6];
            #pragma unroll
            for (int c = 0; c < 6; c++) wv[c] = Ws[k][j0 + c];
            #pragma unroll
            for (int i = 0; i < 4; i++) {
                float hv = hs[te + 16 * i][k];
                #pragma unroll
                for (int c = 0; c < 6; c++) acc[i][c] += hv * wv[c];
            }
        }
        #pragma unroll
        for (int i = 0; i < 4; i++) {
            int n = n0 + te + 16 * i;
            if (n < Nn)
                #pragma unroll
                for (int c = 0; c < 6; c++) Bm[n * 96 + j0 + c] = acc[i][c];
        }
    }
}

// ---------------- per-layer edge kernel (CSR order) ----------------
// u = silu(A[src] + B[dst] + d2*w192 + ea@W1c + eb1); m = silu(u@eW2 + eb2);
// segmented-reduce m by dst -> atomicAdd into agg.
__global__ __launch_bounds__(256, 2)
void k_edge(const float* __restrict__ A, const float* __restrict__ Bm,
            const float* __restrict__ d2, const float* __restrict__ ea,
            const int* __restrict__ perm, const int* __restrict__ ei,
            const float* __restrict__ eW1l, const float* __restrict__ eb1l,
            const float* __restrict__ eW2l, const float* __restrict__ eb2l,
            float* __restrict__ agg) {
    __shared__ float um[64][100];    // u, then overwritten with m
    __shared__ float W2s[96][96];
    __shared__ float W1cs[18][96];   // 0..15: ea-rows of eW1; 16: d2 row; 17: eb1
    __shared__ float eas[64][17];    // ea tile + d2
    __shared__ int pe[64], srcs[64], dsts[64];

    int t = threadIdx.x;
    int e0 = blockIdx.x * 64;
    if (t < 64) pe[t] = perm[e0 + t];
    for (int i = t; i < 96 * 96; i += 256) W2s[i / 96][i % 96] = eW2l[i];
    for (int i = t; i < 16 * 96; i += 256) W1cs[i / 96][i % 96] = eW1l[(193 + i / 96) * 96 + (i % 96)];
    if (t < 96) W1cs[16][t] = eW1l[192 * 96 + t];
    if (t >= 96 && t < 192) W1cs[17][t - 96] = eb1l[t - 96];
    __syncthreads();
    if (t < 64) {
        srcs[t] = ei[pe[t]];
        dsts[t] = ei[Ee + pe[t]];
        eas[t][16] = d2[pe[t]];
    }
    for (int i = t; i < 64 * 16; i += 256) {
        int el = i >> 4, k = i & 15;
        eas[el][k] = ea[pe[el] * EDIM + k];
    }
    __syncthreads();
    // phase 1: u
    for (int idx = t; idx < 64 * 96; idx += 256) {
        int el = idx / 96, j = idx % 96;
        float v = A[srcs[el] * 96 + j] + Bm[dsts[el] * 96 + j] + W1cs[17][j]
                + eas[el][16] * W1cs[16][j];
        #pragma unroll
        for (int k = 0; k < 16; k++) v += eas[el][k] * W1cs[k][j];
        um[el][j] = silu_f(v);
    }
    __syncthreads();
    // phase 2: m = silu(u @ eW2 + eb2)
    int tj = t >> 4, te = t & 15, j0 = tj * 6;
    float acc[4][6];
    #pragma unroll
    for (int i = 0; i < 4; i++)
        #pragma unroll
        for (int c = 0; c < 6; c++) acc[i][c] = eb2l[j0 + c];
    #pragma unroll 4
    for (int k = 0; k < 96; k++) {
        float wv[6];
        #pragma unroll
        for (int c = 0; c < 6; c++) wv[c] = W2s[k][j0 + c];
        #pragma unroll
        for (int i = 0; i < 4; i++) {
            float uv = um[te + 16 * i][k];
            #pragma unroll
            for (int c = 0; c < 6; c++) acc[i][c] += uv * wv[c];
        }
    }
    __syncthreads();
    #pragma unroll
    for (int i = 0; i < 4; i++)
        #pragma unroll
        for (int c = 0; c < 6; c++) um[te + 16 * i][j0 + c] = silu_f(acc[i][c]);
    __syncthreads();
    // segmented reduction by dst (CSR-sorted within block)
    if (t < 192) {
        int j = t % 96, half = t / 96;
        int eb = half * 32, ee = eb + 32;
        float run = 0.f;
        int cd = dsts[eb];
        for (int e = eb; e < ee; e++) {
            int dn = dsts[e];
            if (dn != cd) { atomicAdd(&agg[cd * 96 + j], run); run = 0.f; cd = dn; }
            run += um[e][j];
        }
        atomicAdd(&agg[cd * 96 + j], run);
    }
}

// ---------------- per-layer node MLP + residual ----------------
__global__ __launch_bounds__(256, 2)
void k_node(float* __restrict__ h, const float* __restrict__ agg,
            const float* __restrict__ nW1l, const float* __restrict__ nb1l,
            const float* __restrict__ nW2l, const float* __restrict__ nb2l) {
    __shared__ float hc[64][196];
    __shared__ float t1[64][100];
    int t = threadIdx.x, n0 = blockIdx.x * 64;
    for (int i = t; i < 64 * 192; i += 256) {
        int nl = i / 192, c = i % 192;
        int n = n0 + nl;
        float v = 0.f;
        if (n < Nn) v = (c < 96) ? h[n * 96 + c] : agg[n * 96 + c - 96];
        hc[nl][c] = v;
    }
    __syncthreads();
    int tj = t >> 4, te = t & 15, j0 = tj * 6;
    {
        float acc[4][6];
        #pragma unroll
        for (int i = 0; i < 4; i++)
            #pragma unroll
            for (int c = 0; c < 6; c++) acc[i][c] = nb1l[j0 + c];
        #pragma unroll 4
        for (int k = 0; k < 192; k++) {
            float wv[6];
            #pragma unroll
            for (int c = 0; c < 6; c++) wv[c] = nW1l[k * 96 + j0 + c];
            #pragma unroll
            for (int i = 0; i < 4; i++) {
                float hv = hc[te + 16 * i][k];
                #pragma unroll
                for (int c = 0; c < 6; c++) acc[i][c] += hv * wv[c];
            }
        }
        #pragma unroll
        for (int i = 0; i < 4; i++)
            #pragma unroll
            for (int c = 0; c < 6; c++) t1[te + 16 * i][j0 + c] = silu_f(acc[i][c]);
    }
    __syncthreads();
    {
        float acc[4][6];
        #pragma unroll
        for (int i = 0; i < 4; i++)
            #pragma unroll
            for (int c = 0; c < 6; c++) acc[i][c] = nb2l[j0 + c];
        #pragma unroll 4
        for (int k = 0; k < 96; k++) {
            float wv[6];
            #pragma unroll
            for (int c = 0; c < 6; c++) wv[c] = nW2l[k * 96 + j0 + c];
            #pragma unroll
            for (int i = 0; i < 4; i++) {
                float tv = t1[te + 16 * i][k];
                #pragma unroll
                for (int c = 0; c < 6; c++) acc[i][c] += tv * wv[c];
            }
        }
        #pragma unroll
        for (int i = 0; i < 4; i++) {
            int n = n0 + te + 16 * i;
            if (n < Nn)
                #pragma unroll
                for (int c = 0; c < 6; c++) h[n * 96 + j0 + c] += acc[i][c];
        }
    }
}

// ---------------- pooling ----------------
__global__ void k_pool_partial(const float* __restrict__ h, const int* __restrict__ batch,
                               float* __restrict__ pooled) {
    int g = blockIdx.x >> 2, q = blockIdx.x & 3;
    int start = lower_bound_i(batch, Nn, g);
    int end   = lower_bound_i(batch, Nn, g + 1);
    int len = end - start;
    int chunk = (len + 3) >> 2;
    int s = start + q * chunk;
    int e = min(s + chunk, end);
    int t = threadIdx.x;
    int j = t % 96, r = t / 96;
    float sum = 0.f;
    for (int n = s + r; n < e; n += 2) sum += h[n * 96 + j];
    atomicAdd(&pooled[g * 96 + j], sum);
}

__global__ void k_final(const float* __restrict__ pooled, const int* __restrict__ batch,
                        const float* __restrict__ Wl, const float* __restrict__ bl,
                        float* __restrict__ out) {
    int g = blockIdx.x, lane = threadIdx.x;
    int start = lower_bound_i(batch, Nn, g);
    int end   = lower_bound_i(batch, Nn, g + 1);
    int cnt = end - start; if (cnt < 1) cnt = 1;
    float v = 0.f;
    for (int j = lane; j < 96; j += 64) v += pooled[g * 96 + j] * Wl[j];
    #pragma unroll
    for (int off = 32; off > 0; off >>= 1) v += __shfl_down(v, off);
    if (lane == 0) out[g] = v / (float)cnt + bl[0];
}

extern "C" void kernel_launch(void* const* d_in, const int* in_sizes, int n_in,
                              void* d_out, int out_size, void* d_ws, size_t ws_size,
                              hipStream_t stream) {
    const float* x     = (const float*)d_in[0];
    const float* pos   = (const float*)d_in[1];
    const int*   ei    = (const int*)d_in[2];
    const float* ea    = (const float*)d_in[3];
    const int*   batch = (const int*)d_in[4];
    const float* We    = (const float*)d_in[5];
    const float* be    = (const float*)d_in[6];
    const float* eW1   = (const float*)d_in[7];
    const float* eb1   = (const float*)d_in[8];
    const float* eW2   = (const float*)d_in[9];
    const float* eb2   = (const float*)d_in[10];
    const float* nW1   = (const float*)d_in[11];
    const float* nb1   = (const float*)d_in[12];
    const float* nW2   = (const float*)d_in[13];
    const float* nb2   = (const float*)d_in[14];
    const float* Wl    = (const float*)d_in[15];
    const float* bl    = (const float*)d_in[16];
    float* out = (float*)d_out;

    float* ws = (float*)d_ws;
    float* h      = ws;
    float* A      = ws + 4800000;
    float* Bm     = ws + 9600000;
    float* agg    = ws + 14400000;
    float* d2     = ws + 19200000;   // E floats
    float* pooled = ws + 20000000;   // 50*96
    int* iws      = (int*)(ws + 20016000);
    int* counts   = iws;             // N
    int* cur      = iws + 50000;     // N
    int* rowstart = iws + 100000;    // N+1
    int* bsums    = iws + 150016;    // 256
    int* perm     = iws + 150528;    // E

    hipMemsetAsync(counts, 0, 2 * 50000 * sizeof(int), stream);   // counts + cur
    hipMemsetAsync(pooled, 0, Bb * 96 * sizeof(float), stream);

    k_encoder<<<dim3(3125), dim3(256), 0, stream>>>(x, We, be, h);
    k_prep<<<dim3(3125), dim3(256), 0, stream>>>(ei, pos, d2, counts);
    k_scanA<<<dim3(196), dim3(256), 0, stream>>>(counts, rowstart, bsums);
    k_scanB<<<dim3(1), dim3(256), 0, stream>>>(bsums, 196);
    k_scanC<<<dim3(196), dim3(256), 0, stream>>>(rowstart, bsums);
    k_fill<<<dim3(3125), dim3(256), 0, stream>>>(ei, rowstart, cur, perm);

    for (int l = 0; l < 3; l++) {
        k_AB<<<dim3(782), dim3(256), 0, stream>>>(h, eW1 + l * 209 * 96, A, Bm, agg);
        k_edge<<<dim3(12500), dim3(256), 0, stream>>>(A, Bm, d2, ea, perm, ei,
            eW1 + l * 209 * 96, eb1 + l * 96, eW2 + l * 9216, eb2 + l * 96, agg);
        k_node<<<dim3(782), dim3(256), 0, stream>>>(h, agg,
            nW1 + l * 192 * 96, nb1 + l * 96, nW2 + l * 9216, nb2 + l * 96);
    }
    k_pool_partial<<<dim3(200), dim3(192), 0, stream>>>(h, batch, pooled);
    k_final<<<dim3(50), dim3(64), 0, stream>>>(pooled, batch, Wl, bl, out);
}

// Round 2
// 1713.292 us; speedup vs baseline: 1.5193x; 1.5193x over previous
//
#include <hip/hip_runtime.h>

#define Nn 50000
#define Ee 800000
#define FIN 32
#define Hh 96
#define EDIM 16
#define Bb 50
#define PADU 104   // f16 row pitch (104*2=208 B, 16B-aligned) for u16/W2T

typedef _Float16 half8 __attribute__((ext_vector_type(8)));
typedef float floatx4 __attribute__((ext_vector_type(4)));

__device__ __forceinline__ float silu_f(float x) {
    return x / (1.0f + __expf(-x));
}

__device__ __forceinline__ int lower_bound_i(const int* a, int n, int v) {
    int lo = 0, hi = n;
    while (lo < hi) { int m = (lo + hi) >> 1; if (a[m] < v) lo = m + 1; else hi = m; }
    return lo;
}

// ---------------- encoder: h = x @ We + be ----------------
__global__ void k_encoder(const float* __restrict__ x, const float* __restrict__ We,
                          const float* __restrict__ be, float* __restrict__ h) {
    __shared__ float xs[16][FIN];
    __shared__ float Ws[FIN][Hh];
    int t = threadIdx.x;
    int n0 = blockIdx.x * 16;
    for (int i = t; i < FIN * Hh; i += 256) Ws[i / Hh][i % Hh] = We[i];
    for (int i = t; i < 16 * FIN; i += 256) {
        int n = n0 + i / FIN;
        xs[i / FIN][i % FIN] = (n < Nn) ? x[n * FIN + (i % FIN)] : 0.f;
    }
    __syncthreads();
    for (int idx = t; idx < 16 * Hh; idx += 256) {
        int nl = idx / Hh, j = idx % Hh;
        int n = n0 + nl;
        if (n >= Nn) continue;
        float acc = be[j];
        #pragma unroll
        for (int k = 0; k < FIN; k++) acc += xs[nl][k] * Ws[k][j];
        h[n * Hh + j] = acc;
    }
}

// ---------------- edge prep: d2 + dst histogram ----------------
__global__ void k_prep(const int* __restrict__ ei, const float* __restrict__ pos,
                       float* __restrict__ d2, int* __restrict__ counts) {
    int e = blockIdx.x * 256 + threadIdx.x;
    if (e >= Ee) return;
    int s = ei[e], d = ei[Ee + e];
    float dx = pos[s * 3 + 0] - pos[d * 3 + 0];
    float dy = pos[s * 3 + 1] - pos[d * 3 + 1];
    float dz = pos[s * 3 + 2] - pos[d * 3 + 2];
    d2[e] = dx * dx + dy * dy + dz * dz;
    atomicAdd(&counts[d], 1);
}

// ---------------- two-level exclusive scan -> rowstart ----------------
__global__ void k_scanA(const int* __restrict__ counts, int* __restrict__ rowstart,
                        int* __restrict__ bsums) {
    __shared__ int s[256];
    int b = blockIdx.x, t = threadIdx.x, i = b * 256 + t;
    int v = (i < Nn) ? counts[i] : 0;
    s[t] = v;
    __syncthreads();
    for (int off = 1; off < 256; off <<= 1) {
        int add = (t >= off) ? s[t - off] : 0;
        __syncthreads();
        s[t] += add;
        __syncthreads();
    }
    if (i < Nn) rowstart[i + 1] = s[t];
    if (t == 255) bsums[b] = s[255];
}

__global__ void k_scanB(int* __restrict__ bsums, int nb) {
    __shared__ int s[256];
    int t = threadIdx.x;
    int v = (t < nb) ? bsums[t] : 0;
    s[t] = v;
    __syncthreads();
    for (int off = 1; off < 256; off <<= 1) {
        int add = (t >= off) ? s[t - off] : 0;
        __syncthreads();
        s[t] += add;
        __syncthreads();
    }
    if (t < nb) bsums[t] = s[t] - v;  // exclusive block offsets
}

__global__ void k_scanC(int* __restrict__ rowstart, const int* __restrict__ bsums) {
    int b = blockIdx.x, t = threadIdx.x, i = b * 256 + t;
    if (i < Nn) rowstart[i + 1] += bsums[b];
    if (i == 0 && b == 0) rowstart[0] = 0;
}

// ---------------- CSR fill: perm = edges sorted by dst ----------------
__global__ void k_fill(const int* __restrict__ ei, const int* __restrict__ rowstart,
                       int* __restrict__ cur, int* __restrict__ perm) {
    int e = blockIdx.x * 256 + threadIdx.x;
    if (e >= Ee) return;
    int d = ei[Ee + e];
    int slot = rowstart[d] + atomicAdd(&cur[d], 1);
    perm[slot] = e;
}

// ---------------- per-layer: A = h@W1a, B = h@W1b, zero agg ----------------
__global__ __launch_bounds__(256, 2)
void k_AB(const float* __restrict__ h, const float* __restrict__ eW1l,
          float* __restrict__ A, float* __restrict__ Bm, float* __restrict__ agg) {
    __shared__ float hs[64][100];
    __shared__ float Ws[96][96];
    int t = threadIdx.x;
    int n0 = blockIdx.x * 64;
    for (int i = t; i < 64 * 96; i += 256) {
        int nl = i / 96, c = i % 96;
        int n = n0 + nl;
        float v = (n < Nn) ? h[n * 96 + c] : 0.f;
        hs[nl][c] = v;
        if (n < Nn) agg[n * 96 + c] = 0.f;
    }
    for (int i = t; i < 96 * 96; i += 256) Ws[i / 96][i % 96] = eW1l[i];
    __syncthreads();
    int tj = t >> 4, te = t & 15, j0 = tj * 6;
    // ---- phase A (rows 0..95 of eW1) ----
    {
        float acc[4][6];
        #pragma unroll
        for (int i = 0; i < 4; i++)
            #pragma unroll
            for (int c = 0; c < 6; c++) acc[i][c] = 0.f;
        #pragma unroll 4
        for (int k = 0; k < 96; k++) {
            float wv[6];
            #pragma unroll
            for (int c = 0; c < 6; c++) wv[c] = Ws[k][j0 + c];
            #pragma unroll
            for (int i = 0; i < 4; i++) {
                float hv = hs[te + 16 * i][k];
                #pragma unroll
                for (int c = 0; c < 6; c++) acc[i][c] += hv * wv[c];
            }
        }
        #pragma unroll
        for (int i = 0; i < 4; i++) {
            int n = n0 + te + 16 * i;
            if (n < Nn)
                #pragma unroll
                for (int c = 0; c < 6; c++) A[n * 96 + j0 + c] = acc[i][c];
        }
    }
    __syncthreads();
    for (int i = t; i < 96 * 96; i += 256) Ws[i / 96][i % 96] = eW1l[96 * 96 + i];
    __syncthreads();
    // ---- phase B (rows 96..191 of eW1) ----
    {
        float acc[4][6];
        #pragma unroll
        for (int i = 0; i < 4; i++)
            #pragma unroll
            for (int c = 0; c < 6; c++) acc[i][c] = 0.f;
        #pragma unroll 4
        for (int k = 0; k < 96; k++) {
            float wv[6];
            #pragma unroll
            for (int c = 0; c < 6; c++) wv[c] = Ws[k][j0 + c];
            #pragma unroll
            for (int i = 0; i < 4; i++) {
                float hv = hs[te + 16 * i][k];
                #pragma unroll
                for (int c = 0; c < 6; c++) acc[i][c] += hv * wv[c];
            }
        }
        #pragma unroll
        for (int i = 0; i < 4; i++) {
            int n = n0 + te + 16 * i;
            if (n < Nn)
                #pragma unroll
                for (int c = 0; c < 6; c++) Bm[n * 96 + j0 + c] = acc[i][c];
        }
    }
}

// ---------------- per-layer edge kernel (CSR order, persistent, MFMA phase-2) ----
// u = silu(A[src] + B[dst] + d2*w192 + ea@W1c + eb1)  [fp32 VALU, stored f16]
// m = silu(u @ eW2 + eb2)                             [f16 MFMA 16x16x32]
// segmented-reduce m by dst -> atomicAdd into agg.
__global__ __launch_bounds__(256, 3)
void k_edge(const float* __restrict__ A, const float* __restrict__ Bm,
            const float* __restrict__ d2, const float* __restrict__ ea,
            const int* __restrict__ perm, const int* __restrict__ ei,
            const float* __restrict__ eW1l, const float* __restrict__ eb1l,
            const float* __restrict__ eW2l, const float* __restrict__ eb2l,
            float* __restrict__ agg, int ntiles) {
    __shared__ _Float16 W2T[96][PADU];   // W2T[n][k] = eW2[k][n], f16
    __shared__ _Float16 u16[64][PADU];   // u, later m (f16)
    __shared__ float W1cs[18][96];       // 0..15: ea-rows of eW1; 16: d2 row; 17: eb1
    __shared__ float eb2s[96];
    __shared__ float eas[64][18];        // ea tile + d2 at [16]
    __shared__ int pe[64], srcs[64], dsts[64];

    int t = threadIdx.x;
    int lane = t & 63;
    int quad = lane >> 4, lm = lane & 15;
    int w = t >> 6;                      // wave id == M-tile (16 edges)

    // ---- one-time (per persistent block) weight staging ----
    for (int i = t; i < 96 * 96; i += 256) {
        int k = i / 96, n = i % 96;
        W2T[n][k] = (_Float16)eW2l[i];
    }
    for (int i = t; i < 16 * 96; i += 256)
        W1cs[i / 96][i % 96] = eW1l[(193 + i / 96) * 96 + (i % 96)];
    if (t < 96) { W1cs[16][t] = eW1l[192 * 96 + t]; eb2s[t] = eb2l[t]; }
    if (t >= 96 && t < 192) W1cs[17][t - 96] = eb1l[t - 96];
    __syncthreads();

    // hoist B-fragments into registers (W2T never changes)
    half8 bfrag[6][3];
    #pragma unroll
    for (int nt = 0; nt < 6; nt++)
        #pragma unroll
        for (int kt = 0; kt < 3; kt++)
            bfrag[nt][kt] = *(const half8*)&W2T[nt * 16 + lm][kt * 32 + quad * 8];

    for (int tile = blockIdx.x; tile < ntiles; tile += gridDim.x) {
        int e0 = tile * 64;
        __syncthreads();   // previous tile's readers done before overwriting
        if (t < 64) {
            int p = perm[e0 + t];
            pe[t] = p;
            srcs[t] = ei[p];
            dsts[t] = ei[Ee + p];
            eas[t][16] = d2[p];
        }
        __syncthreads();
        for (int i = t; i < 64 * 16; i += 256) {
            int el = i >> 4, k = i & 15;
            eas[el][k] = ea[pe[el] * EDIM + k];
        }
        __syncthreads();
        // phase 1: u (fp32), store f16
        for (int idx = t; idx < 64 * 96; idx += 256) {
            int el = idx / 96, j = idx % 96;
            float v = A[srcs[el] * 96 + j] + Bm[dsts[el] * 96 + j] + W1cs[17][j]
                    + eas[el][16] * W1cs[16][j];
            #pragma unroll
            for (int k = 0; k < 16; k++) v += eas[el][k] * W1cs[k][j];
            u16[el][j] = (_Float16)silu_f(v);
        }
        __syncthreads();
        // phase 2: load A-frags, MFMA, silu, write m (f16) back into u16
        half8 afrag[3];
        #pragma unroll
        for (int kt = 0; kt < 3; kt++)
            afrag[kt] = *(const half8*)&u16[w * 16 + lm][kt * 32 + quad * 8];
        __syncthreads();
        floatx4 acc[6];
        #pragma unroll
        for (int nt = 0; nt < 6; nt++) {
            float b = eb2s[nt * 16 + lm];
            acc[nt][0] = b; acc[nt][1] = b; acc[nt][2] = b; acc[nt][3] = b;
            acc[nt] = __builtin_amdgcn_mfma_f32_16x16x32_f16(afrag[0], bfrag[nt][0], acc[nt], 0, 0, 0);
            acc[nt] = __builtin_amdgcn_mfma_f32_16x16x32_f16(afrag[1], bfrag[nt][1], acc[nt], 0, 0, 0);
            acc[nt] = __builtin_amdgcn_mfma_f32_16x16x32_f16(afrag[2], bfrag[nt][2], acc[nt], 0, 0, 0);
        }
        #pragma unroll
        for (int nt = 0; nt < 6; nt++)
            #pragma unroll
            for (int r = 0; r < 4; r++)
                u16[w * 16 + quad * 4 + r][nt * 16 + lm] = (_Float16)silu_f(acc[nt][r]);
        __syncthreads();
        // segmented reduction by dst (CSR-sorted within block)
        if (t < 192) {
            int j = t % 96, half_ = t / 96;
            int eb_ = half_ * 32, ee_ = eb_ + 32;
            float run = 0.f;
            int cd = dsts[eb_];
            for (int e = eb_; e < ee_; e++) {
                int dn = dsts[e];
                if (dn != cd) { atomicAdd(&agg[cd * 96 + j], run); run = 0.f; cd = dn; }
                run += (float)u16[e][j];
            }
            atomicAdd(&agg[cd * 96 + j], run);
        }
    }
}

// ---------------- per-layer node MLP + residual ----------------
__global__ __launch_bounds__(256, 2)
void k_node(float* __restrict__ h, const float* __restrict__ agg,
            const float* __restrict__ nW1l, const float* __restrict__ nb1l,
            const float* __restrict__ nW2l, const float* __restrict__ nb2l) {
    __shared__ float hc[64][196];
    __shared__ float t1[64][100];
    int t = threadIdx.x, n0 = blockIdx.x * 64;
    for (int i = t; i < 64 * 192; i += 256) {
        int nl = i / 192, c = i % 192;
        int n = n0 + nl;
        float v = 0.f;
        if (n < Nn) v = (c < 96) ? h[n * 96 + c] : agg[n * 96 + c - 96];
        hc[nl][c] = v;
    }
    __syncthreads();
    int tj = t >> 4, te = t & 15, j0 = tj * 6;
    {
        float acc[4][6];
        #pragma unroll
        for (int i = 0; i < 4; i++)
            #pragma unroll
            for (int c = 0; c < 6; c++) acc[i][c] = nb1l[j0 + c];
        #pragma unroll 4
        for (int k = 0; k < 192; k++) {
            float wv[6];
            #pragma unroll
            for (int c = 0; c < 6; c++) wv[c] = nW1l[k * 96 + j0 + c];
            #pragma unroll
            for (int i = 0; i < 4; i++) {
                float hv = hc[te + 16 * i][k];
                #pragma unroll
                for (int c = 0; c < 6; c++) acc[i][c] += hv * wv[c];
            }
        }
        #pragma unroll
        for (int i = 0; i < 4; i++)
            #pragma unroll
            for (int c = 0; c < 6; c++) t1[te + 16 * i][j0 + c] = silu_f(acc[i][c]);
    }
    __syncthreads();
    {
        float acc[4][6];
        #pragma unroll
        for (int i = 0; i < 4; i++)
            #pragma unroll
            for (int c = 0; c < 6; c++) acc[i][c] = nb2l[j0 + c];
        #pragma unroll 4
        for (int k = 0; k < 96; k++) {
            float wv[6];
            #pragma unroll
            for (int c = 0; c < 6; c++) wv[c] = nW2l[k * 96 + j0 + c];
            #pragma unroll
            for (int i = 0; i < 4; i++) {
                float tv = t1[te + 16 * i][k];
                #pragma unroll
                for (int c = 0; c < 6; c++) acc[i][c] += tv * wv[c];
            }
        }
        #pragma unroll
        for (int i = 0; i < 4; i++) {
            int n = n0 + te + 16 * i;
            if (n < Nn)
                #pragma unroll
                for (int c = 0; c < 6; c++) h[n * 96 + j0 + c] += acc[i][c];
        }
    }
}

// ---------------- pooling ----------------
__global__ void k_pool_partial(const float* __restrict__ h, const int* __restrict__ batch,
                               float* __restrict__ pooled) {
    int g = blockIdx.x >> 2, q = blockIdx.x & 3;
    int start = lower_bound_i(batch, Nn, g);
    int end   = lower_bound_i(batch, Nn, g + 1);
    int len = end - start;
    int chunk = (len + 3) >> 2;
    int s = start + q * chunk;
    int e = min(s + chunk, end);
    int t = threadIdx.x;
    int j = t % 96, r = t / 96;
    float sum = 0.f;
    for (int n = s + r; n < e; n += 2) sum += h[n * 96 + j];
    atomicAdd(&pooled[g * 96 + j], sum);
}

__global__ void k_final(const float* __restrict__ pooled, const int* __restrict__ batch,
                        const float* __restrict__ Wl, const float* __restrict__ bl,
                        float* __restrict__ out) {
    int g = blockIdx.x, lane = threadIdx.x;
    int start = lower_bound_i(batch, Nn, g);
    int end   = lower_bound_i(batch, Nn, g + 1);
    int cnt = end - start; if (cnt < 1) cnt = 1;
    float v = 0.f;
    for (int j = lane; j < 96; j += 64) v += pooled[g * 96 + j] * Wl[j];
    #pragma unroll
    for (int off = 32; off > 0; off >>= 1) v += __shfl_down(v, off);
    if (lane == 0) out[g] = v / (float)cnt + bl[0];
}

extern "C" void kernel_launch(void* const* d_in, const int* in_sizes, int n_in,
                              void* d_out, int out_size, void* d_ws, size_t ws_size,
                              hipStream_t stream) {
    const float* x     = (const float*)d_in[0];
    const float* pos   = (const float*)d_in[1];
    const int*   ei    = (const int*)d_in[2];
    const float* ea    = (const float*)d_in[3];
    const int*   batch = (const int*)d_in[4];
    const float* We    = (const float*)d_in[5];
    const float* be    = (const float*)d_in[6];
    const float* eW1   = (const float*)d_in[7];
    const float* eb1   = (const float*)d_in[8];
    const float* eW2   = (const float*)d_in[9];
    const float* eb2   = (const float*)d_in[10];
    const float* nW1   = (const float*)d_in[11];
    const float* nb1   = (const float*)d_in[12];
    const float* nW2   = (const float*)d_in[13];
    const float* nb2   = (const float*)d_in[14];
    const float* Wl    = (const float*)d_in[15];
    const float* bl    = (const float*)d_in[16];
    float* out = (float*)d_out;

    float* ws = (float*)d_ws;
    float* h      = ws;
    float* A      = ws + 4800000;
    float* Bm     = ws + 9600000;
    float* agg    = ws + 14400000;
    float* d2     = ws + 19200000;   // E floats
    float* pooled = ws + 20000000;   // 50*96
    int* iws      = (int*)(ws + 20016000);
    int* counts   = iws;             // N
    int* cur      = iws + 50000;     // N
    int* rowstart = iws + 100000;    // N+1
    int* bsums    = iws + 150016;    // 256
    int* perm     = iws + 150528;    // E

    hipMemsetAsync(counts, 0, 2 * 50000 * sizeof(int), stream);   // counts + cur
    hipMemsetAsync(pooled, 0, Bb * 96 * sizeof(float), stream);

    k_encoder<<<dim3(3125), dim3(256), 0, stream>>>(x, We, be, h);
    k_prep<<<dim3(3125), dim3(256), 0, stream>>>(ei, pos, d2, counts);
    k_scanA<<<dim3(196), dim3(256), 0, stream>>>(counts, rowstart, bsums);
    k_scanB<<<dim3(1), dim3(256), 0, stream>>>(bsums, 196);
    k_scanC<<<dim3(196), dim3(256), 0, stream>>>(rowstart, bsums);
    k_fill<<<dim3(3125), dim3(256), 0, stream>>>(ei, rowstart, cur, perm);

    for (int l = 0; l < 3; l++) {
        k_AB<<<dim3(782), dim3(256), 0, stream>>>(h, eW1 + l * 209 * 96, A, Bm, agg);
        k_edge<<<dim3(768), dim3(256), 0, stream>>>(A, Bm, d2, ea, perm, ei,
            eW1 + l * 209 * 96, eb1 + l * 96, eW2 + l * 9216, eb2 + l * 96, agg, 12500);
        k_node<<<dim3(782), dim3(256), 0, stream>>>(h, agg,
            nW1 + l * 192 * 96, nb1 + l * 96, nW2 + l * 9216, nb2 + l * 96);
    }
    k_pool_partial<<<dim3(200), dim3(192), 0, stream>>>(h, batch, pooled);
    k_final<<<dim3(50), dim3(64), 0, stream>>>(pooled, batch, Wl, bl, out);
}

// Round 3
// 1312.525 us; speedup vs baseline: 1.9832x; 1.3053x over previous
//
#include <hip/hip_runtime.h>

#define Nn 50000
#define Ee 800000
#define FIN 32
#define Hh 96
#define EDIM 16
#define Bb 50

typedef _Float16 half8 __attribute__((ext_vector_type(8)));
typedef float floatx4 __attribute__((ext_vector_type(4)));

// wT (f16 transposed weights) offsets, in f16 elements
#define OFF_WeT 0
#define WT_LAYER(l) (3072 + (l) * 58368)
#define OFF_W1AB 0        // [192][96]
#define OFF_W1C  18432    // [96][32]
#define OFF_W2   21504    // [96][96]
#define OFF_NW1  30720    // [96][192]
#define OFF_NW2  49152    // [96][96]
#define WT_TOTAL 178176

__device__ __forceinline__ float silu_f(float x) {
    return x / (1.0f + __expf(-x));
}

__device__ __forceinline__ int lower_bound_i(const int* a, int n, int v) {
    int lo = 0, hi = n;
    while (lo < hi) { int m = (lo + hi) >> 1; if (a[m] < v) lo = m + 1; else hi = m; }
    return lo;
}

__device__ __forceinline__ half8 ldg_h8(const _Float16* p) {
    return *(const half8*)p;
}

// ---------------- weight transpose+cast to f16 ----------------
__global__ void k_prepw(const float* __restrict__ We, const float* __restrict__ eW1,
                        const float* __restrict__ eW2, const float* __restrict__ nW1,
                        const float* __restrict__ nW2, _Float16* __restrict__ wT) {
    int idx = blockIdx.x * 256 + threadIdx.x;
    if (idx >= WT_TOTAL) return;
    float v;
    if (idx < 3072) {                       // WeT[n][k] = We[k][n]
        int n = idx >> 5, k = idx & 31;
        v = We[k * 96 + n];
    } else {
        int j = idx - 3072;
        int l = j / 58368, r = j % 58368;
        const float* eW1l = eW1 + l * 209 * 96;
        if (r < 18432) {                    // W1abT[n][k]
            int n = r / 96, k = r % 96;
            v = (n < 96) ? eW1l[k * 96 + n] : eW1l[(96 + k) * 96 + (n - 96)];
        } else if (r < 21504) {             // W1cT[n][k]
            int r2 = r - 18432;
            int n = r2 >> 5, k = r2 & 31;
            v = (k < 16) ? eW1l[(193 + k) * 96 + n]
              : (k == 16) ? eW1l[192 * 96 + n] : 0.f;
        } else if (r < 30720) {             // W2T[n][k]
            int r2 = r - 21504;
            int n = r2 / 96, k = r2 % 96;
            v = eW2[l * 9216 + k * 96 + n];
        } else if (r < 49152) {             // nW1T[n][k]
            int r2 = r - 30720;
            int n = r2 / 192, k = r2 % 192;
            v = nW1[l * 18432 + k * 96 + n];
        } else {                            // nW2T[n][k]
            int r2 = r - 49152;
            int n = r2 / 96, k = r2 % 96;
            v = nW2[l * 9216 + k * 96 + n];
        }
    }
    wT[idx] = (_Float16)v;
}

// ---------------- encoder: h = x @ We + be  (MFMA, K=32) ----------------
__global__ __launch_bounds__(256, 4)
void k_encoder(const float* __restrict__ x, const _Float16* __restrict__ WeT,
               const float* __restrict__ be, float* __restrict__ h) {
    __shared__ _Float16 x16[64][40];
    int t = threadIdx.x;
    int n0 = blockIdx.x * 64;
    for (int i = t; i < 64 * 32; i += 256) {
        int nl = i >> 5, k = i & 31;
        int n = n0 + nl;
        x16[nl][k] = (_Float16)((n < Nn) ? x[n * FIN + k] : 0.f);
    }
    __syncthreads();
    int lane = t & 63, quad = lane >> 4, lm = lane & 15, w = t >> 6;
    half8 af = *(const half8*)&x16[w * 16 + lm][quad * 8];
    for (int nt = 0; nt < 6; nt++) {
        int col = nt * 16 + lm;
        float b = be[col];
        floatx4 acc = {b, b, b, b};
        half8 bf = ldg_h8(WeT + col * 32 + quad * 8);
        acc = __builtin_amdgcn_mfma_f32_16x16x32_f16(af, bf, acc, 0, 0, 0);
        #pragma unroll
        for (int r = 0; r < 4; r++) {
            int n = n0 + w * 16 + quad * 4 + r;
            if (n < Nn) h[n * 96 + col] = acc[r];
        }
    }
}

// ---------------- edge prep: d2 + dst histogram ----------------
__global__ void k_prep(const int* __restrict__ ei, const float* __restrict__ pos,
                       float* __restrict__ d2, int* __restrict__ counts) {
    int e = blockIdx.x * 256 + threadIdx.x;
    if (e >= Ee) return;
    int s = ei[e], d = ei[Ee + e];
    float dx = pos[s * 3 + 0] - pos[d * 3 + 0];
    float dy = pos[s * 3 + 1] - pos[d * 3 + 1];
    float dz = pos[s * 3 + 2] - pos[d * 3 + 2];
    d2[e] = dx * dx + dy * dy + dz * dz;
    atomicAdd(&counts[d], 1);
}

// ---------------- two-level exclusive scan -> rowstart ----------------
__global__ void k_scanA(const int* __restrict__ counts, int* __restrict__ rowstart,
                        int* __restrict__ bsums) {
    __shared__ int s[256];
    int b = blockIdx.x, t = threadIdx.x, i = b * 256 + t;
    int v = (i < Nn) ? counts[i] : 0;
    s[t] = v;
    __syncthreads();
    for (int off = 1; off < 256; off <<= 1) {
        int add = (t >= off) ? s[t - off] : 0;
        __syncthreads();
        s[t] += add;
        __syncthreads();
    }
    if (i < Nn) rowstart[i + 1] = s[t];
    if (t == 255) bsums[b] = s[255];
}

__global__ void k_scanB(int* __restrict__ bsums, int nb) {
    __shared__ int s[256];
    int t = threadIdx.x;
    int v = (t < nb) ? bsums[t] : 0;
    s[t] = v;
    __syncthreads();
    for (int off = 1; off < 256; off <<= 1) {
        int add = (t >= off) ? s[t - off] : 0;
        __syncthreads();
        s[t] += add;
        __syncthreads();
    }
    if (t < nb) bsums[t] = s[t] - v;
}

__global__ void k_scanC(int* __restrict__ rowstart, const int* __restrict__ bsums) {
    int b = blockIdx.x, t = threadIdx.x, i = b * 256 + t;
    if (i < Nn) rowstart[i + 1] += bsums[b];
    if (i == 0 && b == 0) rowstart[0] = 0;
}

__global__ void k_fill(const int* __restrict__ ei, const int* __restrict__ rowstart,
                       int* __restrict__ cur, int* __restrict__ perm) {
    int e = blockIdx.x * 256 + threadIdx.x;
    if (e >= Ee) return;
    int d = ei[Ee + e];
    int slot = rowstart[d] + atomicAdd(&cur[d], 1);
    perm[slot] = e;
}

// ---------------- per-layer: [A|B] = h @ W1ab (MFMA), zero agg ----------------
__global__ __launch_bounds__(256, 4)
void k_ab(const float* __restrict__ h, const _Float16* __restrict__ W1abT,
          _Float16* __restrict__ A16, _Float16* __restrict__ B16,
          float* __restrict__ agg) {
    __shared__ _Float16 h16[64][104];
    int t = threadIdx.x;
    int n0 = blockIdx.x * 64;
    for (int i = t; i < 64 * 96; i += 256) {
        int nl = i / 96, c = i % 96;
        int n = n0 + nl;
        float v = (n < Nn) ? h[n * 96 + c] : 0.f;
        h16[nl][c] = (_Float16)v;
        if (n < Nn) agg[n * 96 + c] = 0.f;
    }
    __syncthreads();
    int lane = t & 63, quad = lane >> 4, lm = lane & 15, w = t >> 6;
    half8 af[3];
    #pragma unroll
    for (int kt = 0; kt < 3; kt++)
        af[kt] = *(const half8*)&h16[w * 16 + lm][kt * 32 + quad * 8];
    for (int nt = 0; nt < 12; nt++) {
        int col = nt * 16 + lm;
        floatx4 acc = {0.f, 0.f, 0.f, 0.f};
        #pragma unroll
        for (int kt = 0; kt < 3; kt++) {
            half8 bf = ldg_h8(W1abT + col * 96 + kt * 32 + quad * 8);
            acc = __builtin_amdgcn_mfma_f32_16x16x32_f16(af[kt], bf, acc, 0, 0, 0);
        }
        #pragma unroll
        for (int r = 0; r < 4; r++) {
            int n = n0 + w * 16 + quad * 4 + r;
            if (n < Nn) {
                if (col < 96) A16[n * 96 + col] = (_Float16)acc[r];
                else          B16[n * 96 + col - 96] = (_Float16)acc[r];
            }
        }
    }
}

// ---------------- per-layer edge kernel (persistent, all-MFMA) ----------------
__global__ __launch_bounds__(256, 4)
void k_edge(const _Float16* __restrict__ A16, const _Float16* __restrict__ B16,
            const float* __restrict__ d2, const float* __restrict__ ea,
            const int* __restrict__ perm, const int* __restrict__ ei,
            const _Float16* __restrict__ W1cT, const float* __restrict__ eb1l,
            const _Float16* __restrict__ W2T, const float* __restrict__ eb2l,
            float* __restrict__ agg, int ntiles) {
    __shared__ _Float16 u16[64][104];   // u, then m
    __shared__ _Float16 ea16[64][32];   // [ea | d2 | zeros]
    __shared__ int pe[64], srcs[64], dsts[64];

    int t = threadIdx.x;
    int lane = t & 63, quad = lane >> 4, lm = lane & 15, w = t >> 6;

    float eb1v[6], eb2v[6];
    #pragma unroll
    for (int nt = 0; nt < 6; nt++) {
        eb1v[nt] = eb1l[nt * 16 + lm];
        eb2v[nt] = eb2l[nt * 16 + lm];
    }

    for (int tile = blockIdx.x; tile < ntiles; tile += gridDim.x) {
        int e0 = tile * 64;
        __syncthreads();   // prev tile's readers done
        if (t < 64) {
            int p = perm[e0 + t];
            pe[t] = p;
            srcs[t] = ei[p];
            dsts[t] = ei[Ee + p];
        }
        __syncthreads();
        for (int i = t; i < 64 * 32; i += 256) {
            int el = i >> 5, k = i & 31;
            float v = (k < 16) ? ea[pe[el] * EDIM + k] : (k == 16 ? d2[pe[el]] : 0.f);
            ea16[el][k] = (_Float16)v;
        }
        __syncthreads();
        // phase 1: u = silu(A[src]+B[dst]+eb1 + [ea|d2]@W1c)
        int srow[4], drow[4];
        #pragma unroll
        for (int r = 0; r < 4; r++) {
            srow[r] = srcs[w * 16 + quad * 4 + r] * 96;
            drow[r] = dsts[w * 16 + quad * 4 + r] * 96;
        }
        half8 af1 = *(const half8*)&ea16[w * 16 + lm][quad * 8];
        for (int nt = 0; nt < 6; nt++) {
            int col = nt * 16 + lm;
            floatx4 acc;
            #pragma unroll
            for (int r = 0; r < 4; r++)
                acc[r] = (float)A16[srow[r] + col] + (float)B16[drow[r] + col] + eb1v[nt];
            half8 bf = ldg_h8(W1cT + col * 32 + quad * 8);
            acc = __builtin_amdgcn_mfma_f32_16x16x32_f16(af1, bf, acc, 0, 0, 0);
            #pragma unroll
            for (int r = 0; r < 4; r++)
                u16[w * 16 + quad * 4 + r][col] = (_Float16)silu_f(acc[r]);
        }
        __syncthreads();
        // phase 2: m = silu(u @ W2 + eb2)
        half8 af2[3];
        #pragma unroll
        for (int kt = 0; kt < 3; kt++)
            af2[kt] = *(const half8*)&u16[w * 16 + lm][kt * 32 + quad * 8];
        __syncthreads();
        for (int nt = 0; nt < 6; nt++) {
            int col = nt * 16 + lm;
            float b = eb2v[nt];
            floatx4 acc = {b, b, b, b};
            #pragma unroll
            for (int kt = 0; kt < 3; kt++) {
                half8 bf = ldg_h8(W2T + col * 96 + kt * 32 + quad * 8);
                acc = __builtin_amdgcn_mfma_f32_16x16x32_f16(af2[kt], bf, acc, 0, 0, 0);
            }
            #pragma unroll
            for (int r = 0; r < 4; r++)
                u16[w * 16 + quad * 4 + r][col] = (_Float16)silu_f(acc[r]);
        }
        __syncthreads();
        // segmented reduction by dst
        if (t < 192) {
            int j = t % 96, half_ = t / 96;
            int eb_ = half_ * 32, ee_ = eb_ + 32;
            float run = 0.f;
            int cd = dsts[eb_];
            for (int e = eb_; e < ee_; e++) {
                int dn = dsts[e];
                if (dn != cd) { atomicAdd(&agg[cd * 96 + j], run); run = 0.f; cd = dn; }
                run += (float)u16[e][j];
            }
            atomicAdd(&agg[cd * 96 + j], run);
        }
    }
}

// ---------------- per-layer node MLP + residual (MFMA) ----------------
__global__ __launch_bounds__(256, 4)
void k_node(float* __restrict__ h, const float* __restrict__ agg,
            const _Float16* __restrict__ nW1T, const float* __restrict__ nb1l,
            const _Float16* __restrict__ nW2T, const float* __restrict__ nb2l) {
    __shared__ _Float16 in16[64][200];   // [h | agg]
    __shared__ _Float16 t116[64][104];
    int t = threadIdx.x, n0 = blockIdx.x * 64;
    for (int i = t; i < 64 * 192; i += 256) {
        int nl = i / 192, c = i % 192;
        int n = n0 + nl;
        float v = 0.f;
        if (n < Nn) v = (c < 96) ? h[n * 96 + c] : agg[n * 96 + c - 96];
        in16[nl][c] = (_Float16)v;
    }
    __syncthreads();
    int lane = t & 63, quad = lane >> 4, lm = lane & 15, w = t >> 6;
    half8 af[6];
    #pragma unroll
    for (int kt = 0; kt < 6; kt++)
        af[kt] = *(const half8*)&in16[w * 16 + lm][kt * 32 + quad * 8];
    for (int nt = 0; nt < 6; nt++) {
        int col = nt * 16 + lm;
        float b = nb1l[col];
        floatx4 acc = {b, b, b, b};
        #pragma unroll
        for (int kt = 0; kt < 6; kt++) {
            half8 bf = ldg_h8(nW1T + col * 192 + kt * 32 + quad * 8);
            acc = __builtin_amdgcn_mfma_f32_16x16x32_f16(af[kt], bf, acc, 0, 0, 0);
        }
        #pragma unroll
        for (int r = 0; r < 4; r++)
            t116[w * 16 + quad * 4 + r][col] = (_Float16)silu_f(acc[r]);
    }
    __syncthreads();
    half8 af2[3];
    #pragma unroll
    for (int kt = 0; kt < 3; kt++)
        af2[kt] = *(const half8*)&t116[w * 16 + lm][kt * 32 + quad * 8];
    for (int nt = 0; nt < 6; nt++) {
        int col = nt * 16 + lm;
        float b = nb2l[col];
        floatx4 acc = {b, b, b, b};
        #pragma unroll
        for (int kt = 0; kt < 3; kt++) {
            half8 bf = ldg_h8(nW2T + col * 96 + kt * 32 + quad * 8);
            acc = __builtin_amdgcn_mfma_f32_16x16x32_f16(af2[kt], bf, acc, 0, 0, 0);
        }
        #pragma unroll
        for (int r = 0; r < 4; r++) {
            int n = n0 + w * 16 + quad * 4 + r;
            if (n < Nn) h[n * 96 + col] += acc[r];
        }
    }
}

// ---------------- pooling ----------------
__global__ void k_pool_partial(const float* __restrict__ h, const int* __restrict__ batch,
                               float* __restrict__ pooled) {
    int g = blockIdx.x >> 2, q = blockIdx.x & 3;
    int start = lower_bound_i(batch, Nn, g);
    int end   = lower_bound_i(batch, Nn, g + 1);
    int len = end - start;
    int chunk = (len + 3) >> 2;
    int s = start + q * chunk;
    int e = min(s + chunk, end);
    int t = threadIdx.x;
    int j = t % 96, r = t / 96;
    float sum = 0.f;
    for (int n = s + r; n < e; n += 2) sum += h[n * 96 + j];
    atomicAdd(&pooled[g * 96 + j], sum);
}

__global__ void k_final(const float* __restrict__ pooled, const int* __restrict__ batch,
                        const float* __restrict__ Wl, const float* __restrict__ bl,
                        float* __restrict__ out) {
    int g = blockIdx.x, lane = threadIdx.x;
    int start = lower_bound_i(batch, Nn, g);
    int end   = lower_bound_i(batch, Nn, g + 1);
    int cnt = end - start; if (cnt < 1) cnt = 1;
    float v = 0.f;
    for (int j = lane; j < 96; j += 64) v += pooled[g * 96 + j] * Wl[j];
    #pragma unroll
    for (int off = 32; off > 0; off >>= 1) v += __shfl_down(v, off);
    if (lane == 0) out[g] = v / (float)cnt + bl[0];
}

extern "C" void kernel_launch(void* const* d_in, const int* in_sizes, int n_in,
                              void* d_out, int out_size, void* d_ws, size_t ws_size,
                              hipStream_t stream) {
    const float* x     = (const float*)d_in[0];
    const float* pos   = (const float*)d_in[1];
    const int*   ei    = (const int*)d_in[2];
    const float* ea    = (const float*)d_in[3];
    const int*   batch = (const int*)d_in[4];
    const float* We    = (const float*)d_in[5];
    const float* be    = (const float*)d_in[6];
    const float* eW1   = (const float*)d_in[7];
    const float* eb1   = (const float*)d_in[8];
    const float* eW2   = (const float*)d_in[9];
    const float* eb2   = (const float*)d_in[10];
    const float* nW1   = (const float*)d_in[11];
    const float* nb1   = (const float*)d_in[12];
    const float* nW2   = (const float*)d_in[13];
    const float* nb2   = (const float*)d_in[14];
    const float* Wl    = (const float*)d_in[15];
    const float* bl    = (const float*)d_in[16];
    float* out = (float*)d_out;

    float* ws = (float*)d_ws;
    float*     h      = ws;                                  // 4.8M f32
    _Float16*  A16    = (_Float16*)(ws + 4800000);           // 4.8M f16
    _Float16*  B16    = (_Float16*)(ws + 7200000);           // 4.8M f16
    float*     agg    = ws + 9600000;                        // 4.8M f32
    float*     d2     = ws + 14400000;                       // 0.8M f32
    float*     pooled = ws + 15200000;                       // 4800 f32
    int*       iws    = (int*)(ws + 15205000);
    int* counts   = iws;             // N
    int* cur      = iws + 50000;     // N
    int* rowstart = iws + 100000;    // N+1
    int* bsums    = iws + 150016;    // 256
    int* perm     = iws + 150528;    // E  (ends at 950528)
    _Float16*  wT     = (_Float16*)(ws + 16155528);          // 178176 f16

    hipMemsetAsync(counts, 0, 2 * 50000 * sizeof(int), stream);
    hipMemsetAsync(pooled, 0, Bb * 96 * sizeof(float), stream);

    k_prepw<<<dim3(696), dim3(256), 0, stream>>>(We, eW1, eW2, nW1, nW2, wT);
    k_encoder<<<dim3(782), dim3(256), 0, stream>>>(x, wT + OFF_WeT, be, h);
    k_prep<<<dim3(3125), dim3(256), 0, stream>>>(ei, pos, d2, counts);
    k_scanA<<<dim3(196), dim3(256), 0, stream>>>(counts, rowstart, bsums);
    k_scanB<<<dim3(1), dim3(256), 0, stream>>>(bsums, 196);
    k_scanC<<<dim3(196), dim3(256), 0, stream>>>(rowstart, bsums);
    k_fill<<<dim3(3125), dim3(256), 0, stream>>>(ei, rowstart, cur, perm);

    for (int l = 0; l < 3; l++) {
        const _Float16* wl = wT + WT_LAYER(l);
        k_ab<<<dim3(782), dim3(256), 0, stream>>>(h, wl + OFF_W1AB, A16, B16, agg);
        k_edge<<<dim3(1024), dim3(256), 0, stream>>>(A16, B16, d2, ea, perm, ei,
            wl + OFF_W1C, eb1 + l * 96, wl + OFF_W2, eb2 + l * 96, agg, 12500);
        k_node<<<dim3(782), dim3(256), 0, stream>>>(h, agg,
            wl + OFF_NW1, nb1 + l * 96, wl + OFF_NW2, nb2 + l * 96);
    }
    k_pool_partial<<<dim3(200), dim3(192), 0, stream>>>(h, batch, pooled);
    k_final<<<dim3(50), dim3(64), 0, stream>>>(pooled, batch, Wl, bl, out);
}

// Round 5
// 1134.110 us; speedup vs baseline: 2.2952x; 1.1573x over previous
//
#include <hip/hip_runtime.h>

#define Nn 50000
#define Ee 800000
#define FIN 32
#define EDIM 16
#define Bb 50
#define NTILES 12500
#define TPX 1563   // tiles per XCD (8*1563 >= 12500)

typedef _Float16 half8 __attribute__((ext_vector_type(8)));
typedef float floatx4 __attribute__((ext_vector_type(4)));

// wT (f16 transposed weights) offsets, in f16 elements
#define OFF_WeT 0
#define WT_LAYER(l) (3072 + (l) * 58368)
#define OFF_W1AB 0        // [192][96]
#define OFF_W1C  18432    // [96][32]
#define OFF_W2   21504    // [96][96]
#define OFF_NW1  30720    // [96][192]
#define OFF_NW2  49152    // [96][96]
#define WT_TOTAL 178176

__device__ __forceinline__ float silu_f(float x) {
    return x / (1.0f + __expf(-x));
}

__device__ __forceinline__ int lower_bound_i(const int* a, int n, int v) {
    int lo = 0, hi = n;
    while (lo < hi) { int m = (lo + hi) >> 1; if (a[m] < v) lo = m + 1; else hi = m; }
    return lo;
}

__device__ __forceinline__ half8 ldg_h8(const _Float16* p) {
    return *(const half8*)p;
}

__device__ __forceinline__ half8 h8_zero() {
    half8 z;
    #pragma unroll
    for (int j = 0; j < 8; j++) z[j] = (_Float16)0.f;
    return z;
}

// ---------------- weight transpose+cast to f16 ----------------
__global__ void k_prepw(const float* __restrict__ We, const float* __restrict__ eW1,
                        const float* __restrict__ eW2, const float* __restrict__ nW1,
                        const float* __restrict__ nW2, _Float16* __restrict__ wT) {
    int idx = blockIdx.x * 256 + threadIdx.x;
    if (idx >= WT_TOTAL) return;
    float v;
    if (idx < 3072) {                       // WeT[n][k]
        int n = idx >> 5, k = idx & 31;
        v = We[k * 96 + n];
    } else {
        int j = idx - 3072;
        int l = j / 58368, r = j % 58368;
        const float* eW1l = eW1 + l * 209 * 96;
        if (r < 18432) {                    // W1abT[n][k]
            int n = r / 96, k = r % 96;
            v = (n < 96) ? eW1l[k * 96 + n] : eW1l[(96 + k) * 96 + (n - 96)];
        } else if (r < 21504) {             // W1cT[n][k]
            int r2 = r - 18432;
            int n = r2 >> 5, k = r2 & 31;
            v = (k < 16) ? eW1l[(193 + k) * 96 + n]
              : (k == 16) ? eW1l[192 * 96 + n] : 0.f;
        } else if (r < 30720) {             // W2T[n][k]
            int r2 = r - 21504;
            int n = r2 / 96, k = r2 % 96;
            v = eW2[l * 9216 + k * 96 + n];
        } else if (r < 49152) {             // nW1T[n][k]
            int r2 = r - 30720;
            int n = r2 / 192, k = r2 % 192;
            v = nW1[l * 18432 + k * 96 + n];
        } else {                            // nW2T[n][k]
            int r2 = r - 49152;
            int n = r2 / 96, k = r2 % 96;
            v = nW2[l * 9216 + k * 96 + n];
        }
    }
    wT[idx] = (_Float16)v;
}

// ---------------- edge prep: d2 + dst histogram ----------------
__global__ void k_prep(const int* __restrict__ ei, const float* __restrict__ pos,
                       float* __restrict__ d2, int* __restrict__ counts) {
    int e = blockIdx.x * 256 + threadIdx.x;
    if (e >= Ee) return;
    int s = ei[e], d = ei[Ee + e];
    float dx = pos[s * 3 + 0] - pos[d * 3 + 0];
    float dy = pos[s * 3 + 1] - pos[d * 3 + 1];
    float dz = pos[s * 3 + 2] - pos[d * 3 + 2];
    d2[e] = dx * dx + dy * dy + dz * dz;
    atomicAdd(&counts[d], 1);
}

// ---------------- two-level exclusive scan -> rowstart ----------------
__global__ void k_scanA(const int* __restrict__ counts, int* __restrict__ rowstart,
                        int* __restrict__ bsums) {
    __shared__ int s[256];
    int b = blockIdx.x, t = threadIdx.x, i = b * 256 + t;
    int v = (i < Nn) ? counts[i] : 0;
    s[t] = v;
    __syncthreads();
    for (int off = 1; off < 256; off <<= 1) {
        int add = (t >= off) ? s[t - off] : 0;
        __syncthreads();
        s[t] += add;
        __syncthreads();
    }
    if (i < Nn) rowstart[i + 1] = s[t];
    if (t == 255) bsums[b] = s[255];
}

__global__ void k_scanB(int* __restrict__ bsums, int nb) {
    __shared__ int s[256];
    int t = threadIdx.x;
    int v = (t < nb) ? bsums[t] : 0;
    s[t] = v;
    __syncthreads();
    for (int off = 1; off < 256; off <<= 1) {
        int add = (t >= off) ? s[t - off] : 0;
        __syncthreads();
        s[t] += add;
        __syncthreads();
    }
    if (t < nb) bsums[t] = s[t] - v;
}

__global__ void k_scanC(int* __restrict__ rowstart, const int* __restrict__ bsums) {
    int b = blockIdx.x, t = threadIdx.x, i = b * 256 + t;
    if (i < Nn) rowstart[i + 1] += bsums[b];
    if (i == 0 && b == 0) rowstart[0] = 0;
}

// ---------------- CSR fill + pre-permuted edge data ----------------
__global__ void k_fill(const int* __restrict__ ei, const float* __restrict__ ea,
                       const float* __restrict__ d2, const int* __restrict__ rowstart,
                       int* __restrict__ cur, int* __restrict__ srcs_p,
                       int* __restrict__ dsts_p, _Float16* __restrict__ eap16) {
    int e = blockIdx.x * 256 + threadIdx.x;
    if (e >= Ee) return;
    int s = ei[e], d = ei[Ee + e];
    int slot = rowstart[d] + atomicAdd(&cur[d], 1);
    srcs_p[slot] = s;
    dsts_p[slot] = d;
    const float4* ea4 = (const float4*)ea;
    float4 q0 = ea4[e * 4 + 0], q1 = ea4[e * 4 + 1];
    float4 q2 = ea4[e * 4 + 2], q3 = ea4[e * 4 + 3];
    float dv = d2[e];
    half8 c0, c1, c2, c3;
    c0[0]=(_Float16)q0.x; c0[1]=(_Float16)q0.y; c0[2]=(_Float16)q0.z; c0[3]=(_Float16)q0.w;
    c0[4]=(_Float16)q1.x; c0[5]=(_Float16)q1.y; c0[6]=(_Float16)q1.z; c0[7]=(_Float16)q1.w;
    c1[0]=(_Float16)q2.x; c1[1]=(_Float16)q2.y; c1[2]=(_Float16)q2.z; c1[3]=(_Float16)q2.w;
    c1[4]=(_Float16)q3.x; c1[5]=(_Float16)q3.y; c1[6]=(_Float16)q3.z; c1[7]=(_Float16)q3.w;
    c2 = h8_zero(); c3 = h8_zero();
    c2[0] = (_Float16)dv;
    half8* dst8 = (half8*)(eap16 + (size_t)slot * 32);
    dst8[0] = c0; dst8[1] = c1; dst8[2] = c2; dst8[3] = c3;
}

// ---------------- encoder + A/B(l0) + zero agg ----------------
__global__ __launch_bounds__(256, 4)
void k_encab(const float* __restrict__ x, const _Float16* __restrict__ WeT,
             const float* __restrict__ be, const _Float16* __restrict__ W1abT,
             _Float16* __restrict__ h16, _Float16* __restrict__ A16,
             _Float16* __restrict__ B16, float* __restrict__ agg) {
    __shared__ _Float16 x16[64][40];
    __shared__ _Float16 hs[64][104];
    int t = threadIdx.x;
    int n0 = blockIdx.x * 64;
    for (int i = t; i < 64 * 32; i += 256) {
        int nl = i >> 5, k = i & 31;
        int n = n0 + nl;
        x16[nl][k] = (_Float16)((n < Nn) ? x[n * FIN + k] : 0.f);
    }
    __syncthreads();
    int lane = t & 63, quad = lane >> 4, lm = lane & 15, w = t >> 6;
    half8 af = *(const half8*)&x16[w * 16 + lm][quad * 8];
    for (int nt = 0; nt < 6; nt++) {
        int col = nt * 16 + lm;
        float b = be[col];
        floatx4 acc = {b, b, b, b};
        half8 bf = ldg_h8(WeT + col * 32 + quad * 8);
        acc = __builtin_amdgcn_mfma_f32_16x16x32_f16(af, bf, acc, 0, 0, 0);
        #pragma unroll
        for (int r = 0; r < 4; r++)
            hs[w * 16 + quad * 4 + r][col] = (_Float16)acc[r];
    }
    __syncthreads();
    // coalesced h16 write + zero agg
    #pragma unroll
    for (int i = 0; i < 3; i++) {
        int ci = t + 256 * i;
        int el = ci / 12, c0 = (ci % 12) * 8;
        int n = n0 + el;
        if (n < Nn) *(half8*)(h16 + n * 96 + c0) = *(half8*)&hs[el][c0];
    }
    for (int i = t; i < 64 * 24; i += 256) {
        int el = i / 24, c = (i % 24) * 4;
        int n = n0 + el;
        if (n < Nn) *(float4*)(agg + n * 96 + c) = make_float4(0.f, 0.f, 0.f, 0.f);
    }
    // A/B for layer 0
    half8 af3[3];
    #pragma unroll
    for (int kt = 0; kt < 3; kt++)
        af3[kt] = *(const half8*)&hs[w * 16 + lm][kt * 32 + quad * 8];
    for (int nt = 0; nt < 12; nt++) {
        int col = nt * 16 + lm;
        floatx4 acc = {0.f, 0.f, 0.f, 0.f};
        #pragma unroll
        for (int kt = 0; kt < 3; kt++) {
            half8 bf = ldg_h8(W1abT + col * 96 + kt * 32 + quad * 8);
            acc = __builtin_amdgcn_mfma_f32_16x16x32_f16(af3[kt], bf, acc, 0, 0, 0);
        }
        #pragma unroll
        for (int r = 0; r < 4; r++) {
            int n = n0 + w * 16 + quad * 4 + r;
            if (n < Nn) {
                if (col < 96) A16[n * 96 + col] = (_Float16)acc[r];
                else          B16[n * 96 + col - 96] = (_Float16)acc[r];
            }
        }
    }
}

// ---------------- per-layer edge kernel (persistent, XCD-chunked) ----------------
__global__ __launch_bounds__(256, 3)
void k_edge(const _Float16* __restrict__ A16, const _Float16* __restrict__ B16,
            const _Float16* __restrict__ eap16, const int* __restrict__ srcs_p,
            const int* __restrict__ dsts_p, const _Float16* __restrict__ W1cT,
            const float* __restrict__ eb1l, const _Float16* __restrict__ W2T,
            const float* __restrict__ eb2l, float* __restrict__ agg) {
    __shared__ _Float16 u16[64][104];
    __shared__ int srcs_s[64], dsts_s[64];

    int t = threadIdx.x;
    int lane = t & 63, quad = lane >> 4, lm = lane & 15, w = t >> 6;

    float eb1v[6], eb2v[6];
    half8 w2f[6][3];
    #pragma unroll
    for (int nt = 0; nt < 6; nt++) {
        eb1v[nt] = eb1l[nt * 16 + lm];
        eb2v[nt] = eb2l[nt * 16 + lm];
        #pragma unroll
        for (int kt = 0; kt < 3; kt++)
            w2f[nt][kt] = ldg_h8(W2T + (nt * 16 + lm) * 96 + kt * 32 + quad * 8);
    }

    int xcd = blockIdx.x & 7, ib = blockIdx.x >> 3;
    for (int k = ib; k < TPX; k += 128) {
        int tile = xcd * TPX + k;
        if (tile >= NTILES) break;
        int e0 = tile * 64;
        __syncthreads();   // prev tile fully consumed
        if (t < 64) {
            srcs_s[t] = srcs_p[e0 + t];
            dsts_s[t] = dsts_p[e0 + t];
        }
        // phase 1a: pre = eb1 + [ea|d2] @ W1c  -> u16 (C layout)
        half8 af1 = ldg_h8(eap16 + (size_t)(e0 + w * 16 + lm) * 32 + quad * 8);
        __syncthreads();
        for (int nt = 0; nt < 6; nt++) {
            int col = nt * 16 + lm;
            floatx4 acc = {eb1v[nt], eb1v[nt], eb1v[nt], eb1v[nt]};
            half8 bf = ldg_h8(W1cT + col * 32 + quad * 8);
            acc = __builtin_amdgcn_mfma_f32_16x16x32_f16(af1, bf, acc, 0, 0, 0);
            #pragma unroll
            for (int r = 0; r < 4; r++)
                u16[w * 16 + quad * 4 + r][col] = (_Float16)acc[r];
        }
        __syncthreads();
        // phase 1b: u = silu(pre + A[src] + B[dst]), vectorized row chunks
        #pragma unroll
        for (int i = 0; i < 3; i++) {
            int ci = t + 256 * i;
            int el = ci / 12, c0 = (ci % 12) * 8;
            half8 av = ldg_h8(A16 + srcs_s[el] * 96 + c0);
            half8 bv = ldg_h8(B16 + dsts_s[el] * 96 + c0);
            half8 pv = *(half8*)&u16[el][c0];
            half8 res;
            #pragma unroll
            for (int j = 0; j < 8; j++)
                res[j] = (_Float16)silu_f((float)pv[j] + (float)av[j] + (float)bv[j]);
            *(half8*)&u16[el][c0] = res;
        }
        __syncthreads();
        // phase 2: m = silu(u @ W2 + eb2)
        half8 af2[3];
        #pragma unroll
        for (int kt = 0; kt < 3; kt++)
            af2[kt] = *(const half8*)&u16[w * 16 + lm][kt * 32 + quad * 8];
        __syncthreads();
        for (int nt = 0; nt < 6; nt++) {
            floatx4 acc = {eb2v[nt], eb2v[nt], eb2v[nt], eb2v[nt]};
            #pragma unroll
            for (int kt = 0; kt < 3; kt++)
                acc = __builtin_amdgcn_mfma_f32_16x16x32_f16(af2[kt], w2f[nt][kt], acc, 0, 0, 0);
            #pragma unroll
            for (int r = 0; r < 4; r++)
                u16[w * 16 + quad * 4 + r][nt * 16 + lm] = (_Float16)silu_f(acc[r]);
        }
        __syncthreads();
        // segmented reduction by dst
        if (t < 192) {
            int j = t % 96, half_ = t / 96;
            int eb_ = half_ * 32, ee_ = eb_ + 32;
            float run = 0.f;
            int cd = dsts_s[eb_];
            for (int e = eb_; e < ee_; e++) {
                int dn = dsts_s[e];
                if (dn != cd) { atomicAdd(&agg[cd * 96 + j], run); run = 0.f; cd = dn; }
                run += (float)u16[e][j];
            }
            atomicAdd(&agg[cd * 96 + j], run);
        }
    }
}

// ---------------- node MLP + residual + next-layer A/B ----------------
__global__ __launch_bounds__(256, 4)
void k_nodeab(_Float16* __restrict__ h16, float* __restrict__ agg,
              const _Float16* __restrict__ nW1T, const float* __restrict__ nb1l,
              const _Float16* __restrict__ nW2T, const float* __restrict__ nb2l,
              const _Float16* __restrict__ W1abT, _Float16* __restrict__ A16,
              _Float16* __restrict__ B16, int do_ab) {
    __shared__ _Float16 in16[64][200];   // [h | agg] f16
    __shared__ _Float16 t116[64][104];
    int t = threadIdx.x, n0 = blockIdx.x * 64;
    #pragma unroll
    for (int i = 0; i < 3; i++) {
        int ci = t + 256 * i;
        int el = ci / 12, c0 = (ci % 12) * 8;
        int n = n0 + el;
        half8 hv = h8_zero();
        half8 av = h8_zero();
        if (n < Nn) {
            hv = ldg_h8(h16 + n * 96 + c0);
            float4 a = *(const float4*)(agg + n * 96 + c0);
            float4 b = *(const float4*)(agg + n * 96 + c0 + 4);
            av[0]=(_Float16)a.x; av[1]=(_Float16)a.y; av[2]=(_Float16)a.z; av[3]=(_Float16)a.w;
            av[4]=(_Float16)b.x; av[5]=(_Float16)b.y; av[6]=(_Float16)b.z; av[7]=(_Float16)b.w;
        }
        *(half8*)&in16[el][c0] = hv;
        *(half8*)&in16[el][96 + c0] = av;
    }
    __syncthreads();
    int lane = t & 63, quad = lane >> 4, lm = lane & 15, w = t >> 6;
    half8 af[6];
    #pragma unroll
    for (int kt = 0; kt < 6; kt++)
        af[kt] = *(const half8*)&in16[w * 16 + lm][kt * 32 + quad * 8];
    for (int nt = 0; nt < 6; nt++) {
        int col = nt * 16 + lm;
        float b = nb1l[col];
        floatx4 acc = {b, b, b, b};
        #pragma unroll
        for (int kt = 0; kt < 6; kt++) {
            half8 bf = ldg_h8(nW1T + col * 192 + kt * 32 + quad * 8);
            acc = __builtin_amdgcn_mfma_f32_16x16x32_f16(af[kt], bf, acc, 0, 0, 0);
        }
        #pragma unroll
        for (int r = 0; r < 4; r++)
            t116[w * 16 + quad * 4 + r][col] = (_Float16)silu_f(acc[r]);
    }
    __syncthreads();
    half8 af2[3];
    #pragma unroll
    for (int kt = 0; kt < 3; kt++)
        af2[kt] = *(const half8*)&t116[w * 16 + lm][kt * 32 + quad * 8];
    __syncthreads();
    for (int nt = 0; nt < 6; nt++) {
        int col = nt * 16 + lm;
        float b = nb2l[col];
        floatx4 acc = {b, b, b, b};
        #pragma unroll
        for (int kt = 0; kt < 3; kt++) {
            half8 bf = ldg_h8(nW2T + col * 96 + kt * 32 + quad * 8);
            acc = __builtin_amdgcn_mfma_f32_16x16x32_f16(af2[kt], bf, acc, 0, 0, 0);
        }
        // residual: h_new = h_old + upd, write back into in16 (same owner thread)
        #pragma unroll
        for (int r = 0; r < 4; r++) {
            int row = w * 16 + quad * 4 + r;
            float hnew = (float)in16[row][col] + acc[r];
            in16[row][col] = (_Float16)hnew;
        }
    }
    __syncthreads();
    // coalesced h16 write + optional next-layer A/B + agg rezero
    #pragma unroll
    for (int i = 0; i < 3; i++) {
        int ci = t + 256 * i;
        int el = ci / 12, c0 = (ci % 12) * 8;
        int n = n0 + el;
        if (n < Nn) *(half8*)(h16 + n * 96 + c0) = *(half8*)&in16[el][c0];
    }
    if (!do_ab) return;
    half8 af3[3];
    #pragma unroll
    for (int kt = 0; kt < 3; kt++)
        af3[kt] = *(const half8*)&in16[w * 16 + lm][kt * 32 + quad * 8];
    for (int nt = 0; nt < 12; nt++) {
        int col = nt * 16 + lm;
        floatx4 acc = {0.f, 0.f, 0.f, 0.f};
        #pragma unroll
        for (int kt = 0; kt < 3; kt++) {
            half8 bf = ldg_h8(W1abT + col * 96 + kt * 32 + quad * 8);
            acc = __builtin_amdgcn_mfma_f32_16x16x32_f16(af3[kt], bf, acc, 0, 0, 0);
        }
        #pragma unroll
        for (int r = 0; r < 4; r++) {
            int n = n0 + w * 16 + quad * 4 + r;
            if (n < Nn) {
                if (col < 96) A16[n * 96 + col] = (_Float16)acc[r];
                else          B16[n * 96 + col - 96] = (_Float16)acc[r];
            }
        }
    }
    for (int i = t; i < 64 * 24; i += 256) {
        int el = i / 24, c = (i % 24) * 4;
        int n = n0 + el;
        if (n < Nn) *(float4*)(agg + n * 96 + c) = make_float4(0.f, 0.f, 0.f, 0.f);
    }
}

// ---------------- pooling ----------------
__global__ void k_pool_partial(const _Float16* __restrict__ h16, const int* __restrict__ batch,
                               float* __restrict__ pooled) {
    int g = blockIdx.x >> 2, q = blockIdx.x & 3;
    int start = lower_bound_i(batch, Nn, g);
    int end   = lower_bound_i(batch, Nn, g + 1);
    int len = end - start;
    int chunk = (len + 3) >> 2;
    int s = start + q * chunk;
    int e = min(s + chunk, end);
    int t = threadIdx.x;
    int j = t % 96, r = t / 96;
    float sum = 0.f;
    for (int n = s + r; n < e; n += 2) sum += (float)h16[n * 96 + j];
    atomicAdd(&pooled[g * 96 + j], sum);
}

__global__ void k_final(const float* __restrict__ pooled, const int* __restrict__ batch,
                        const float* __restrict__ Wl, const float* __restrict__ bl,
                        float* __restrict__ out) {
    int g = blockIdx.x, lane = threadIdx.x;
    int start = lower_bound_i(batch, Nn, g);
    int end   = lower_bound_i(batch, Nn, g + 1);
    int cnt = end - start; if (cnt < 1) cnt = 1;
    float v = 0.f;
    for (int j = lane; j < 96; j += 64) v += pooled[g * 96 + j] * Wl[j];
    #pragma unroll
    for (int off = 32; off > 0; off >>= 1) v += __shfl_down(v, off);
    if (lane == 0) out[g] = v / (float)cnt + bl[0];
}

extern "C" void kernel_launch(void* const* d_in, const int* in_sizes, int n_in,
                              void* d_out, int out_size, void* d_ws, size_t ws_size,
                              hipStream_t stream) {
    const float* x     = (const float*)d_in[0];
    const float* pos   = (const float*)d_in[1];
    const int*   ei    = (const int*)d_in[2];
    const float* ea    = (const float*)d_in[3];
    const int*   batch = (const int*)d_in[4];
    const float* We    = (const float*)d_in[5];
    const float* be    = (const float*)d_in[6];
    const float* eW1   = (const float*)d_in[7];
    const float* eb1   = (const float*)d_in[8];
    const float* eW2   = (const float*)d_in[9];
    const float* eb2   = (const float*)d_in[10];
    const float* nW1   = (const float*)d_in[11];
    const float* nb1   = (const float*)d_in[12];
    const float* nW2   = (const float*)d_in[13];
    const float* nb2   = (const float*)d_in[14];
    const float* Wl    = (const float*)d_in[15];
    const float* bl    = (const float*)d_in[16];
    float* out = (float*)d_out;

    float* ws = (float*)d_ws;
    _Float16* h16    = (_Float16*)(ws);                 // 4.8M halfs
    _Float16* A16    = (_Float16*)(ws + 2400000);       // 4.8M halfs
    _Float16* B16    = (_Float16*)(ws + 4800000);       // 4.8M halfs
    float*    agg    = ws + 7200000;                    // 4.8M f32
    float*    d2     = ws + 12000000;                   // 0.8M f32
    float*    pooled = ws + 12800000;                   // 4800
    int*      counts   = (int*)(ws + 12804800);         // 50000
    int*      cur      = (int*)(ws + 12854800);         // 50000
    int*      rowstart = (int*)(ws + 12904800);         // 50001
    int*      bsums    = (int*)(ws + 12954816);         // 256
    int*      srcs_p   = (int*)(ws + 12955072);         // 800000
    int*      dsts_p   = (int*)(ws + 13755072);         // 800000
    _Float16* eap16    = (_Float16*)(ws + 14555072);    // 25.6M halfs
    _Float16* wT       = (_Float16*)(ws + 27355072);    // 178176 halfs

    hipMemsetAsync(counts, 0, 2 * 50000 * sizeof(int), stream);
    hipMemsetAsync(pooled, 0, Bb * 96 * sizeof(float), stream);

    k_prepw<<<dim3(696), dim3(256), 0, stream>>>(We, eW1, eW2, nW1, nW2, wT);
    k_prep<<<dim3(3125), dim3(256), 0, stream>>>(ei, pos, d2, counts);
    k_scanA<<<dim3(196), dim3(256), 0, stream>>>(counts, rowstart, bsums);
    k_scanB<<<dim3(1), dim3(256), 0, stream>>>(bsums, 196);
    k_scanC<<<dim3(196), dim3(256), 0, stream>>>(rowstart, bsums);
    k_fill<<<dim3(3125), dim3(256), 0, stream>>>(ei, ea, d2, rowstart, cur,
                                                 srcs_p, dsts_p, eap16);
    k_encab<<<dim3(782), dim3(256), 0, stream>>>(x, wT + OFF_WeT, be,
        wT + WT_LAYER(0) + OFF_W1AB, h16, A16, B16, agg);

    for (int l = 0; l < 3; l++) {
        const _Float16* wl = wT + WT_LAYER(l);
        k_edge<<<dim3(1024), dim3(256), 0, stream>>>(A16, B16, eap16, srcs_p, dsts_p,
            wl + OFF_W1C, eb1 + l * 96, wl + OFF_W2, eb2 + l * 96, agg);
        const _Float16* wnext = wT + WT_LAYER(l < 2 ? l + 1 : 0);
        k_nodeab<<<dim3(782), dim3(256), 0, stream>>>(h16, agg,
            wl + OFF_NW1, nb1 + l * 96, wl + OFF_NW2, nb2 + l * 96,
            wnext + OFF_W1AB, A16, B16, (l < 2) ? 1 : 0);
    }
    k_pool_partial<<<dim3(200), dim3(192), 0, stream>>>(h16, batch, pooled);
    k_final<<<dim3(50), dim3(64), 0, stream>>>(pooled, batch, Wl, bl, out);
}

// Round 6
// 776.161 us; speedup vs baseline: 3.3537x; 1.4612x over previous
//
#include <hip/hip_runtime.h>

#define Nn 50000
#define Ee 800000
#define FIN 32
#define EDIM 16
#define Bb 50
#define NTILES 12500
#define TPX 1563   // tiles per XCD (8*1563 >= 12500)

typedef _Float16 half8 __attribute__((ext_vector_type(8)));
typedef float floatx4 __attribute__((ext_vector_type(4)));

// wT (f16 transposed weights) offsets, in f16 elements
#define OFF_WeT 0
#define WT_LAYER(l) (3072 + (l) * 58368)
#define OFF_W1AB 0        // [192][96]
#define OFF_W1C  18432    // [96][32]
#define OFF_W2   21504    // [96][96]
#define OFF_NW1  30720    // [96][192]
#define OFF_NW2  49152    // [96][96]
#define WT_TOTAL 178176

__device__ __forceinline__ float silu_f(float x) {
    return x / (1.0f + __expf(-x));
}

__device__ __forceinline__ int lower_bound_i(const int* a, int n, int v) {
    int lo = 0, hi = n;
    while (lo < hi) { int m = (lo + hi) >> 1; if (a[m] < v) lo = m + 1; else hi = m; }
    return lo;
}

__device__ __forceinline__ half8 ldg_h8(const _Float16* p) {
    return *(const half8*)p;
}

__device__ __forceinline__ half8 h8_zero() {
    half8 z;
    #pragma unroll
    for (int j = 0; j < 8; j++) z[j] = (_Float16)0.f;
    return z;
}

// ---------------- weight transpose+cast to f16 ----------------
__global__ void k_prepw(const float* __restrict__ We, const float* __restrict__ eW1,
                        const float* __restrict__ eW2, const float* __restrict__ nW1,
                        const float* __restrict__ nW2, _Float16* __restrict__ wT) {
    int idx = blockIdx.x * 256 + threadIdx.x;
    if (idx >= WT_TOTAL) return;
    float v;
    if (idx < 3072) {                       // WeT[n][k]
        int n = idx >> 5, k = idx & 31;
        v = We[k * 96 + n];
    } else {
        int j = idx - 3072;
        int l = j / 58368, r = j % 58368;
        const float* eW1l = eW1 + l * 209 * 96;
        if (r < 18432) {                    // W1abT[n][k]
            int n = r / 96, k = r % 96;
            v = (n < 96) ? eW1l[k * 96 + n] : eW1l[(96 + k) * 96 + (n - 96)];
        } else if (r < 21504) {             // W1cT[n][k]
            int r2 = r - 18432;
            int n = r2 >> 5, k = r2 & 31;
            v = (k < 16) ? eW1l[(193 + k) * 96 + n]
              : (k == 16) ? eW1l[192 * 96 + n] : 0.f;
        } else if (r < 30720) {             // W2T[n][k]
            int r2 = r - 21504;
            int n = r2 / 96, k = r2 % 96;
            v = eW2[l * 9216 + k * 96 + n];
        } else if (r < 49152) {             // nW1T[n][k]
            int r2 = r - 30720;
            int n = r2 / 192, k = r2 % 192;
            v = nW1[l * 18432 + k * 96 + n];
        } else {                            // nW2T[n][k]
            int r2 = r - 49152;
            int n = r2 / 96, k = r2 % 96;
            v = nW2[l * 9216 + k * 96 + n];
        }
    }
    wT[idx] = (_Float16)v;
}

// ---------------- edge prep: d2 + dst histogram ----------------
__global__ void k_prep(const int* __restrict__ ei, const float* __restrict__ pos,
                       float* __restrict__ d2, int* __restrict__ counts) {
    int e = blockIdx.x * 256 + threadIdx.x;
    if (e >= Ee) return;
    int s = ei[e], d = ei[Ee + e];
    float dx = pos[s * 3 + 0] - pos[d * 3 + 0];
    float dy = pos[s * 3 + 1] - pos[d * 3 + 1];
    float dz = pos[s * 3 + 2] - pos[d * 3 + 2];
    d2[e] = dx * dx + dy * dy + dz * dz;
    atomicAdd(&counts[d], 1);
}

// ---------------- two-level exclusive scan -> rowstart ----------------
__global__ void k_scanA(const int* __restrict__ counts, int* __restrict__ rowstart,
                        int* __restrict__ bsums) {
    __shared__ int s[256];
    int b = blockIdx.x, t = threadIdx.x, i = b * 256 + t;
    int v = (i < Nn) ? counts[i] : 0;
    s[t] = v;
    __syncthreads();
    for (int off = 1; off < 256; off <<= 1) {
        int add = (t >= off) ? s[t - off] : 0;
        __syncthreads();
        s[t] += add;
        __syncthreads();
    }
    if (i < Nn) rowstart[i + 1] = s[t];
    if (t == 255) bsums[b] = s[255];
}

__global__ void k_scanB(int* __restrict__ bsums, int nb) {
    __shared__ int s[256];
    int t = threadIdx.x;
    int v = (t < nb) ? bsums[t] : 0;
    s[t] = v;
    __syncthreads();
    for (int off = 1; off < 256; off <<= 1) {
        int add = (t >= off) ? s[t - off] : 0;
        __syncthreads();
        s[t] += add;
        __syncthreads();
    }
    if (t < nb) bsums[t] = s[t] - v;
}

__global__ void k_scanC(int* __restrict__ rowstart, const int* __restrict__ bsums) {
    int b = blockIdx.x, t = threadIdx.x, i = b * 256 + t;
    if (i < Nn) rowstart[i + 1] += bsums[b];
    if (i == 0 && b == 0) rowstart[0] = 0;
}

// ---------------- CSR fill + pre-permuted edge data ----------------
__global__ void k_fill(const int* __restrict__ ei, const float* __restrict__ ea,
                       const float* __restrict__ d2, const int* __restrict__ rowstart,
                       int* __restrict__ cur, int* __restrict__ srcs_p,
                       int* __restrict__ dsts_p, _Float16* __restrict__ eap16,
                       _Float16* __restrict__ d2h) {
    int e = blockIdx.x * 256 + threadIdx.x;
    if (e >= Ee) return;
    int s = ei[e], d = ei[Ee + e];
    int slot = rowstart[d] + atomicAdd(&cur[d], 1);
    srcs_p[slot] = s;
    dsts_p[slot] = d;
    const float4* ea4 = (const float4*)ea;
    float4 q0 = ea4[e * 4 + 0], q1 = ea4[e * 4 + 1];
    float4 q2 = ea4[e * 4 + 2], q3 = ea4[e * 4 + 3];
    half8 c0, c1;
    c0[0]=(_Float16)q0.x; c0[1]=(_Float16)q0.y; c0[2]=(_Float16)q0.z; c0[3]=(_Float16)q0.w;
    c0[4]=(_Float16)q1.x; c0[5]=(_Float16)q1.y; c0[6]=(_Float16)q1.z; c0[7]=(_Float16)q1.w;
    c1[0]=(_Float16)q2.x; c1[1]=(_Float16)q2.y; c1[2]=(_Float16)q2.z; c1[3]=(_Float16)q2.w;
    c1[4]=(_Float16)q3.x; c1[5]=(_Float16)q3.y; c1[6]=(_Float16)q3.z; c1[7]=(_Float16)q3.w;
    half8* dst8 = (half8*)(eap16 + (size_t)slot * 16);
    dst8[0] = c0; dst8[1] = c1;
    d2h[slot] = (_Float16)d2[e];
}

// ---------------- encoder + A/B(l0) + zero agg ----------------
__global__ __launch_bounds__(256, 4)
void k_encab(const float* __restrict__ x, const _Float16* __restrict__ WeT,
             const float* __restrict__ be, const _Float16* __restrict__ W1abT,
             _Float16* __restrict__ h16, _Float16* __restrict__ A16,
             _Float16* __restrict__ B16, float* __restrict__ agg) {
    __shared__ _Float16 x16[64][40];
    __shared__ _Float16 hs[64][104];
    int t = threadIdx.x;
    int n0 = blockIdx.x * 64;
    for (int i = t; i < 64 * 32; i += 256) {
        int nl = i >> 5, k = i & 31;
        int n = n0 + nl;
        x16[nl][k] = (_Float16)((n < Nn) ? x[n * FIN + k] : 0.f);
    }
    __syncthreads();
    int lane = t & 63, quad = lane >> 4, lm = lane & 15, w = t >> 6;
    half8 af = *(const half8*)&x16[w * 16 + lm][quad * 8];
    for (int nt = 0; nt < 6; nt++) {
        int col = nt * 16 + lm;
        float b = be[col];
        floatx4 acc = {b, b, b, b};
        half8 bf = ldg_h8(WeT + col * 32 + quad * 8);
        acc = __builtin_amdgcn_mfma_f32_16x16x32_f16(af, bf, acc, 0, 0, 0);
        #pragma unroll
        for (int r = 0; r < 4; r++)
            hs[w * 16 + quad * 4 + r][col] = (_Float16)acc[r];
    }
    __syncthreads();
    // coalesced h16 write + zero agg
    #pragma unroll
    for (int i = 0; i < 3; i++) {
        int ci = t + 256 * i;
        int el = ci / 12, c0 = (ci % 12) * 8;
        int n = n0 + el;
        if (n < Nn) *(half8*)(h16 + n * 96 + c0) = *(half8*)&hs[el][c0];
    }
    for (int i = t; i < 64 * 24; i += 256) {
        int el = i / 24, c = (i % 24) * 4;
        int n = n0 + el;
        if (n < Nn) *(float4*)(agg + n * 96 + c) = make_float4(0.f, 0.f, 0.f, 0.f);
    }
    // A/B for layer 0
    half8 af3[3];
    #pragma unroll
    for (int kt = 0; kt < 3; kt++)
        af3[kt] = *(const half8*)&hs[w * 16 + lm][kt * 32 + quad * 8];
    for (int nt = 0; nt < 12; nt++) {
        int col = nt * 16 + lm;
        floatx4 acc = {0.f, 0.f, 0.f, 0.f};
        #pragma unroll
        for (int kt = 0; kt < 3; kt++) {
            half8 bf = ldg_h8(W1abT + col * 96 + kt * 32 + quad * 8);
            acc = __builtin_amdgcn_mfma_f32_16x16x32_f16(af3[kt], bf, acc, 0, 0, 0);
        }
        #pragma unroll
        for (int r = 0; r < 4; r++) {
            int n = n0 + w * 16 + quad * 4 + r;
            if (n < Nn) {
                if (col < 96) A16[n * 96 + col] = (_Float16)acc[r];
                else          B16[n * 96 + col - 96] = (_Float16)acc[r];
            }
        }
    }
}

// ---------------- per-layer edge kernel (persistent, XCD-chunked) ----------------
__global__ __launch_bounds__(256, 4)
void k_edge(const _Float16* __restrict__ A16, const _Float16* __restrict__ B16,
            const _Float16* __restrict__ eap16, const _Float16* __restrict__ d2h,
            const int* __restrict__ srcs_p, const int* __restrict__ dsts_p,
            const _Float16* __restrict__ W1cT, const float* __restrict__ eb1l,
            const _Float16* __restrict__ W2T, const float* __restrict__ eb2l,
            float* __restrict__ agg) {
    __shared__ _Float16 u16[64][104];
    __shared__ _Float16 W2s[96][104];   // staged once per block
    __shared__ int srcs_s[64], dsts_s[64];

    int t = threadIdx.x;
    int lane = t & 63, quad = lane >> 4, lm = lane & 15, w = t >> 6;

    // stage W2 once per persistent block
    for (int i = t; i < 96 * 96; i += 256) W2s[i / 96][i % 96] = W2T[i];

    float eb1v[6], eb2v[6];
    #pragma unroll
    for (int nt = 0; nt < 6; nt++) {
        eb1v[nt] = eb1l[nt * 16 + lm];
        eb2v[nt] = eb2l[nt * 16 + lm];
    }
    __syncthreads();

    int xcd = blockIdx.x & 7, ib = blockIdx.x >> 3;
    for (int k = ib; k < TPX; k += 128) {
        int tile = xcd * TPX + k;
        if (tile >= NTILES) break;
        int e0 = tile * 64;
        // global loads issued before the barrier: overlap prev tile's reduction
        int sv = 0, dv = 0;
        if (t < 64) { sv = srcs_p[e0 + t]; dv = dsts_p[e0 + t]; }
        int erow = e0 + w * 16 + lm;
        half8 af1;
        if (quad == 0)      af1 = ldg_h8(eap16 + (size_t)erow * 16);
        else if (quad == 1) af1 = ldg_h8(eap16 + (size_t)erow * 16 + 8);
        else { af1 = h8_zero(); if (quad == 2) af1[0] = d2h[erow]; }
        __syncthreads();   // prev tile fully consumed
        if (t < 64) { srcs_s[t] = sv; dsts_s[t] = dv; }
        // phase 1a: pre = eb1 + [ea|d2] @ W1c -> u16 (C layout)
        for (int nt = 0; nt < 6; nt++) {
            int col = nt * 16 + lm;
            floatx4 acc = {eb1v[nt], eb1v[nt], eb1v[nt], eb1v[nt]};
            half8 bf = ldg_h8(W1cT + col * 32 + quad * 8);
            acc = __builtin_amdgcn_mfma_f32_16x16x32_f16(af1, bf, acc, 0, 0, 0);
            #pragma unroll
            for (int r = 0; r < 4; r++)
                u16[w * 16 + quad * 4 + r][col] = (_Float16)acc[r];
        }
        __syncthreads();
        // phase 1b: u = silu(pre + A[src] + B[dst]), vectorized row chunks
        #pragma unroll
        for (int i = 0; i < 3; i++) {
            int ci = t + 256 * i;
            int el = ci / 12, c0 = (ci % 12) * 8;
            half8 av = ldg_h8(A16 + srcs_s[el] * 96 + c0);
            half8 bv = ldg_h8(B16 + dsts_s[el] * 96 + c0);
            half8 pv = *(half8*)&u16[el][c0];
            half8 res;
            #pragma unroll
            for (int j = 0; j < 8; j++)
                res[j] = (_Float16)silu_f((float)pv[j] + (float)av[j] + (float)bv[j]);
            *(half8*)&u16[el][c0] = res;
        }
        __syncthreads();
        // phase 2: m = silu(u @ W2 + eb2)
        half8 af2[3];
        #pragma unroll
        for (int kt = 0; kt < 3; kt++)
            af2[kt] = *(const half8*)&u16[w * 16 + lm][kt * 32 + quad * 8];
        __syncthreads();
        for (int nt = 0; nt < 6; nt++) {
            int col = nt * 16 + lm;
            floatx4 acc = {eb2v[nt], eb2v[nt], eb2v[nt], eb2v[nt]};
            #pragma unroll
            for (int kt = 0; kt < 3; kt++) {
                half8 bf = *(const half8*)&W2s[col][kt * 32 + quad * 8];
                acc = __builtin_amdgcn_mfma_f32_16x16x32_f16(af2[kt], bf, acc, 0, 0, 0);
            }
            #pragma unroll
            for (int r = 0; r < 4; r++)
                u16[w * 16 + quad * 4 + r][col] = (_Float16)silu_f(acc[r]);
        }
        __syncthreads();
        // segmented reduction by dst
        if (t < 192) {
            int j = t % 96, half_ = t / 96;
            int eb_ = half_ * 32, ee_ = eb_ + 32;
            float run = 0.f;
            int cd = dsts_s[eb_];
            for (int e = eb_; e < ee_; e++) {
                int dn = dsts_s[e];
                if (dn != cd) { atomicAdd(&agg[cd * 96 + j], run); run = 0.f; cd = dn; }
                run += (float)u16[e][j];
            }
            atomicAdd(&agg[cd * 96 + j], run);
        }
    }
}

// ---------------- node MLP + residual + next-layer A/B ----------------
__global__ __launch_bounds__(256, 4)
void k_nodeab(_Float16* __restrict__ h16, float* __restrict__ agg,
              const _Float16* __restrict__ nW1T, const float* __restrict__ nb1l,
              const _Float16* __restrict__ nW2T, const float* __restrict__ nb2l,
              const _Float16* __restrict__ W1abT, _Float16* __restrict__ A16,
              _Float16* __restrict__ B16, int do_ab) {
    __shared__ _Float16 in16[64][200];   // [h | agg] f16
    __shared__ _Float16 t116[64][104];
    int t = threadIdx.x, n0 = blockIdx.x * 64;
    #pragma unroll
    for (int i = 0; i < 3; i++) {
        int ci = t + 256 * i;
        int el = ci / 12, c0 = (ci % 12) * 8;
        int n = n0 + el;
        half8 hv = h8_zero();
        half8 av = h8_zero();
        if (n < Nn) {
            hv = ldg_h8(h16 + n * 96 + c0);
            float4 a = *(const float4*)(agg + n * 96 + c0);
            float4 b = *(const float4*)(agg + n * 96 + c0 + 4);
            av[0]=(_Float16)a.x; av[1]=(_Float16)a.y; av[2]=(_Float16)a.z; av[3]=(_Float16)a.w;
            av[4]=(_Float16)b.x; av[5]=(_Float16)b.y; av[6]=(_Float16)b.z; av[7]=(_Float16)b.w;
        }
        *(half8*)&in16[el][c0] = hv;
        *(half8*)&in16[el][96 + c0] = av;
    }
    __syncthreads();
    int lane = t & 63, quad = lane >> 4, lm = lane & 15, w = t >> 6;
    half8 af[6];
    #pragma unroll
    for (int kt = 0; kt < 6; kt++)
        af[kt] = *(const half8*)&in16[w * 16 + lm][kt * 32 + quad * 8];
    for (int nt = 0; nt < 6; nt++) {
        int col = nt * 16 + lm;
        float b = nb1l[col];
        floatx4 acc = {b, b, b, b};
        #pragma unroll
        for (int kt = 0; kt < 6; kt++) {
            half8 bf = ldg_h8(nW1T + col * 192 + kt * 32 + quad * 8);
            acc = __builtin_amdgcn_mfma_f32_16x16x32_f16(af[kt], bf, acc, 0, 0, 0);
        }
        #pragma unroll
        for (int r = 0; r < 4; r++)
            t116[w * 16 + quad * 4 + r][col] = (_Float16)silu_f(acc[r]);
    }
    __syncthreads();
    half8 af2[3];
    #pragma unroll
    for (int kt = 0; kt < 3; kt++)
        af2[kt] = *(const half8*)&t116[w * 16 + lm][kt * 32 + quad * 8];
    __syncthreads();
    for (int nt = 0; nt < 6; nt++) {
        int col = nt * 16 + lm;
        float b = nb2l[col];
        floatx4 acc = {b, b, b, b};
        #pragma unroll
        for (int kt = 0; kt < 3; kt++) {
            half8 bf = ldg_h8(nW2T + col * 96 + kt * 32 + quad * 8);
            acc = __builtin_amdgcn_mfma_f32_16x16x32_f16(af2[kt], bf, acc, 0, 0, 0);
        }
        // residual: h_new = h_old + upd (same owner thread)
        #pragma unroll
        for (int r = 0; r < 4; r++) {
            int row = w * 16 + quad * 4 + r;
            float hnew = (float)in16[row][col] + acc[r];
            in16[row][col] = (_Float16)hnew;
        }
    }
    __syncthreads();
    // coalesced h16 write + optional next-layer A/B + agg rezero
    #pragma unroll
    for (int i = 0; i < 3; i++) {
        int ci = t + 256 * i;
        int el = ci / 12, c0 = (ci % 12) * 8;
        int n = n0 + el;
        if (n < Nn) *(half8*)(h16 + n * 96 + c0) = *(half8*)&in16[el][c0];
    }
    if (!do_ab) return;
    half8 af3[3];
    #pragma unroll
    for (int kt = 0; kt < 3; kt++)
        af3[kt] = *(const half8*)&in16[w * 16 + lm][kt * 32 + quad * 8];
    for (int nt = 0; nt < 12; nt++) {
        int col = nt * 16 + lm;
        floatx4 acc = {0.f, 0.f, 0.f, 0.f};
        #pragma unroll
        for (int kt = 0; kt < 3; kt++) {
            half8 bf = ldg_h8(W1abT + col * 96 + kt * 32 + quad * 8);
            acc = __builtin_amdgcn_mfma_f32_16x16x32_f16(af3[kt], bf, acc, 0, 0, 0);
        }
        #pragma unroll
        for (int r = 0; r < 4; r++) {
            int n = n0 + w * 16 + quad * 4 + r;
            if (n < Nn) {
                if (col < 96) A16[n * 96 + col] = (_Float16)acc[r];
                else          B16[n * 96 + col - 96] = (_Float16)acc[r];
            }
        }
    }
    for (int i = t; i < 64 * 24; i += 256) {
        int el = i / 24, c = (i % 24) * 4;
        int n = n0 + el;
        if (n < Nn) *(float4*)(agg + n * 96 + c) = make_float4(0.f, 0.f, 0.f, 0.f);
    }
}

// ---------------- pooling ----------------
__global__ void k_pool_partial(const _Float16* __restrict__ h16, const int* __restrict__ batch,
                               float* __restrict__ pooled) {
    int g = blockIdx.x >> 2, q = blockIdx.x & 3;
    int start = lower_bound_i(batch, Nn, g);
    int end   = lower_bound_i(batch, Nn, g + 1);
    int len = end - start;
    int chunk = (len + 3) >> 2;
    int s = start + q * chunk;
    int e = min(s + chunk, end);
    int t = threadIdx.x;
    int j = t % 96, r = t / 96;
    float sum = 0.f;
    for (int n = s + r; n < e; n += 2) sum += (float)h16[n * 96 + j];
    atomicAdd(&pooled[g * 96 + j], sum);
}

__global__ void k_final(const float* __restrict__ pooled, const int* __restrict__ batch,
                        const float* __restrict__ Wl, const float* __restrict__ bl,
                        float* __restrict__ out) {
    int g = blockIdx.x, lane = threadIdx.x;
    int start = lower_bound_i(batch, Nn, g);
    int end   = lower_bound_i(batch, Nn, g + 1);
    int cnt = end - start; if (cnt < 1) cnt = 1;
    float v = 0.f;
    for (int j = lane; j < 96; j += 64) v += pooled[g * 96 + j] * Wl[j];
    #pragma unroll
    for (int off = 32; off > 0; off >>= 1) v += __shfl_down(v, off);
    if (lane == 0) out[g] = v / (float)cnt + bl[0];
}

extern "C" void kernel_launch(void* const* d_in, const int* in_sizes, int n_in,
                              void* d_out, int out_size, void* d_ws, size_t ws_size,
                              hipStream_t stream) {
    const float* x     = (const float*)d_in[0];
    const float* pos   = (const float*)d_in[1];
    const int*   ei    = (const int*)d_in[2];
    const float* ea    = (const float*)d_in[3];
    const int*   batch = (const int*)d_in[4];
    const float* We    = (const float*)d_in[5];
    const float* be    = (const float*)d_in[6];
    const float* eW1   = (const float*)d_in[7];
    const float* eb1   = (const float*)d_in[8];
    const float* eW2   = (const float*)d_in[9];
    const float* eb2   = (const float*)d_in[10];
    const float* nW1   = (const float*)d_in[11];
    const float* nb1   = (const float*)d_in[12];
    const float* nW2   = (const float*)d_in[13];
    const float* nb2   = (const float*)d_in[14];
    const float* Wl    = (const float*)d_in[15];
    const float* bl    = (const float*)d_in[16];
    float* out = (float*)d_out;

    float* ws = (float*)d_ws;
    _Float16* h16    = (_Float16*)(ws);                 // 4.8M halfs
    _Float16* A16    = (_Float16*)(ws + 2400000);       // 4.8M halfs
    _Float16* B16    = (_Float16*)(ws + 4800000);       // 4.8M halfs
    float*    agg    = ws + 7200000;                    // 4.8M f32
    float*    d2     = ws + 12000000;                   // 0.8M f32
    float*    pooled = ws + 12800000;                   // 4800
    int*      counts   = (int*)(ws + 12804800);         // 50000
    int*      cur      = (int*)(ws + 12854800);         // 50000
    int*      rowstart = (int*)(ws + 12904800);         // 50001
    int*      bsums    = (int*)(ws + 12954816);         // 256
    int*      srcs_p   = (int*)(ws + 12955072);         // 800000
    int*      dsts_p   = (int*)(ws + 13755072);         // 800000
    _Float16* eap16    = (_Float16*)(ws + 14555072);    // 12.8M halfs
    _Float16* d2h      = (_Float16*)(ws + 20955072);    // 0.8M halfs
    _Float16* wT       = (_Float16*)(ws + 21355072);    // 178176 halfs

    hipMemsetAsync(counts, 0, 2 * 50000 * sizeof(int), stream);
    hipMemsetAsync(pooled, 0, Bb * 96 * sizeof(float), stream);

    k_prepw<<<dim3(696), dim3(256), 0, stream>>>(We, eW1, eW2, nW1, nW2, wT);
    k_prep<<<dim3(3125), dim3(256), 0, stream>>>(ei, pos, d2, counts);
    k_scanA<<<dim3(196), dim3(256), 0, stream>>>(counts, rowstart, bsums);
    k_scanB<<<dim3(1), dim3(256), 0, stream>>>(bsums, 196);
    k_scanC<<<dim3(196), dim3(256), 0, stream>>>(rowstart, bsums);
    k_fill<<<dim3(3125), dim3(256), 0, stream>>>(ei, ea, d2, rowstart, cur,
                                                 srcs_p, dsts_p, eap16, d2h);
    k_encab<<<dim3(782), dim3(256), 0, stream>>>(x, wT + OFF_WeT, be,
        wT + WT_LAYER(0) + OFF_W1AB, h16, A16, B16, agg);

    for (int l = 0; l < 3; l++) {
        const _Float16* wl = wT + WT_LAYER(l);
        k_edge<<<dim3(1024), dim3(256), 0, stream>>>(A16, B16, eap16, d2h,
            srcs_p, dsts_p, wl + OFF_W1C, eb1 + l * 96, wl + OFF_W2, eb2 + l * 96, agg);
        const _Float16* wnext = wT + WT_LAYER(l < 2 ? l + 1 : 0);
        k_nodeab<<<dim3(782), dim3(256), 0, stream>>>(h16, agg,
            wl + OFF_NW1, nb1 + l * 96, wl + OFF_NW2, nb2 + l * 96,
            wnext + OFF_W1AB, A16, B16, (l < 2) ? 1 : 0);
    }
    k_pool_partial<<<dim3(200), dim3(192), 0, stream>>>(h16, batch, pooled);
    k_final<<<dim3(50), dim3(64), 0, stream>>>(pooled, batch, Wl, bl, out);
}